// Round 8
// baseline (207.756 us; speedup 1.0000x reference)
//
#include <hip/hip_runtime.h>
#include <hip/hip_fp16.h>

// QLinear with per-k fp16 requantized accumulation (mptorch fma semantics).
// out = q16( q16_scan_fma( q8(x) @ q8(W)^T ) + q8(b) )
//
// Round-8: x moved to the SCALAR pipe. Round-7 proved ds_read_b128 cost is
// per-instruction (~12 cyc full register return; broadcast no discount), so
// the fix is fewer LDS instructions: wave tile 16m x 64n, lane 16m x 1n.
//  - x: wave-uniform 16 m-rows -> s_load_dwordx16 per k-pair into SGPRs
//    (v_pk_fma_f16 may read 1 SGPR operand). No LDS, no VMEM, no per-lane
//    register return. Plain C loads from a readfirstlane-uniform pointer
//    (no asm loads -- rounds 5/6's clobber class excluded).
//  - w: ONE ds_read_b32 per k-pair (lane -> consecutive u32, 2-way = free).
//  - per-CU per k-pair: VALU 64 cyc/SIMD (wall), LDS ~46, SMEM 512 B
//    -> VALU-bound. pk_fma splat moves to w via op_sel.

#define M_DIM 2048
#define N_DIM 1024
#define K_DIM 1024

#define BM 64
#define BN 64
#define BK 64
#define NCHUNK (K_DIM / BK)   // 16

typedef unsigned u32;
typedef u32 su16 __attribute__((ext_vector_type(16)));

// exact E4M3 (exp=4, man=3) quantization of an fp32 value, result fp32
__device__ __forceinline__ float quant_e4m3(float v) {
  unsigned au = __float_as_uint(v) & 0x7fffffffu;
  if (au == 0u) return v;                 // +-0
  int e = (int)(au >> 23) - 127;          // floor(log2|v|) for normals
  if (e < -6) e = -6;                     // fp32 subnorms hit the clamp too
  float s  = __uint_as_float((unsigned)(130 - e) << 23);  // 2^(3-e), exact
  float is = __uint_as_float((unsigned)(124 + e) << 23);  // 2^(e-3), exact
  float r = rintf(v * s) * is;            // RNE (half-to-even), all steps exact
  return fminf(240.f, fmaxf(-240.f, r));
}

// ---------- fused prep ----------
// blocks [0,2048): x [M][K] -> xQ[K/2][M/2][2] u32:
//   (tp, mp, j) = { q(x[2mp][2tp+j]) lo, q(x[2mp+1][2tp+j]) hi }
//   (linear col index mp*2+j == original m-col layout -> same indexing as xP)
// blocks [2048,3072): w [N][K] -> wK[K/2][N] u32:
//   (tp, n) = { q(w[n][2tp]) lo, q(w[n][2tp+1]) hi }
__global__ __launch_bounds__(256) void prep_kernel(const float* __restrict__ x,
                                                   const float* __restrict__ w,
                                                   u32* __restrict__ xQ,
                                                   u32* __restrict__ wK) {
  __shared__ float tile[32][33];
  const int tx = threadIdx.x & 31;
  const int ty = threadIdx.x >> 5;
  if (blockIdx.x < 2048) {
    const int c0 = (blockIdx.x & 31) * 32;   // k offset
    const int r0 = (blockIdx.x >> 5) * 32;   // m offset
#pragma unroll
    for (int i = 0; i < 4; i++) {
      int r = r0 + ty + i * 8;
      tile[ty + i * 8][tx] = quant_e4m3(x[(size_t)r * K_DIM + c0 + tx]);  // [m_l][k_l]
    }
    __syncthreads();
#pragma unroll
    for (int i = 0; i < 2; i++) {
      int tl = ty + i * 8;                   // k-pair local 0..15
      int mp = tx >> 1;                      // m-pair local 0..15
      int j = tx & 1;                        // k half
      u32 lo = (u32)__half_as_ushort(__float2half(tile[2 * mp][2 * tl + j]));
      u32 hi = (u32)__half_as_ushort(__float2half(tile[2 * mp + 1][2 * tl + j]));
      xQ[(size_t)(c0 / 2 + tl) * M_DIM + r0 + tx] = lo | (hi << 16);
    }
  } else {
    const int b = blockIdx.x - 2048;
    const int k0 = (b & 31) * 32;
    const int n0 = (b >> 5) * 32;
#pragma unroll
    for (int i = 0; i < 4; i++) {
      int n = n0 + ty + i * 8;
      tile[ty + i * 8][tx] = quant_e4m3(w[(size_t)n * K_DIM + k0 + tx]);  // [n_l][k_l]
    }
    __syncthreads();
#pragma unroll
    for (int i = 0; i < 2; i++) {
      int tl = ty + i * 8;                   // k-pair local 0..15
      u32 lo = (u32)__half_as_ushort(__float2half(tile[tx][2 * tl]));
      u32 hi = (u32)__half_as_ushort(__float2half(tile[tx][2 * tl + 1]));
      wK[(size_t)(k0 / 2 + tl) * N_DIM + n0 + tx] = lo | (hi << 16);
    }
  }
}

// ---------- GEMM ----------

__device__ __forceinline__ void gld16(const void* g, void* l) {
  __builtin_amdgcn_global_load_lds((const __attribute__((address_space(1))) u32*)g,
                                   (__attribute__((address_space(3))) u32*)l, 16, 0, 0);
}

// acc(pair of adjacent m) += x(pair) * splat(w.lo)   -- k0 of the packed pair
// dst.lo = fma(x.lo, w.lo, acc.lo); dst.hi = fma(x.hi, w.lo, acc.hi)
__device__ __forceinline__ void pk_k0(u32& acc, u32 x, u32 w) {
  asm("v_pk_fma_f16 %0, %1, %2, %0 op_sel:[0,0,0] op_sel_hi:[1,0,1]"
      : "+v"(acc) : "s"(x), "v"(w));
}
// acc += x(pair) * splat(w.hi)                        -- k1 of the packed pair
__device__ __forceinline__ void pk_k1(u32& acc, u32 x, u32 w) {
  asm("v_pk_fma_f16 %0, %1, %2, %0 op_sel:[0,1,0] op_sel_hi:[1,1,1]"
      : "+v"(acc) : "s"(x), "v"(w));
}

// xQ [K/2][M] u32 (m-pair packed), wK [K/2][N] u32 (k-pair packed), b [N],
// out [M][N] fp32.  256 threads = 4 waves; block tile 64m x 64n; wave tile
// 16m x 64n (waves stack in m); lane = one n column x 16 m (8 m-pairs).
__global__ __launch_bounds__(256, 2) void gemm_qfma(const u32* __restrict__ xQ,
                                                    const u32* __restrict__ wK,
                                                    const float* __restrict__ b,
                                                    float* __restrict__ outp) {
  __shared__ __align__(16) u32 wsh[2][BK / 2][BN];   // 2 x 32 x 64 u32 = 16 KB
  const int tid = threadIdx.x;
  const int lane = tid & 63;                                 // n column
  const int uw = __builtin_amdgcn_readfirstlane(tid >> 6);   // wave id, uniform
  const int bn0 = blockIdx.x * BN;
  const int bm0 = blockIdx.y * BM;

  u32 acc[8];
#pragma unroll
  for (int i = 0; i < 8; i++) acc[i] = 0u;

  // w staging: linear LDS (wave-uniform base + lane*16), per-lane global src
  const u32* wsrc = wK + (size_t)(tid >> 4) * N_DIM + bn0 + ((tid & 15) << 2);
  auto stage = [&](int ch, int buf) {
    const u32* wp = wsrc + (size_t)ch * (BK / 2) * N_DIM;
    char* wl = (char*)&wsh[buf][0][0] + tid * 16;
    gld16(wp, wl);                                  // rows 0..15
    gld16(wp + (size_t)16 * N_DIM, wl + 4096);      // rows 16..31
  };

  // x: uniform pointer to this wave's 16 m-rows (8 m-pairs), 64 B per k-pair
  const u32* const xw = xQ + bm0 + uw * 16;

  auto compute = [&](int ch, int buf) {
#pragma unroll
    for (int tp = 0; tp < BK / 2; tp++) {   // k-pair: k0=2tp, k1=2tp+1
      const su16 xv = *reinterpret_cast<const su16*>(
          xw + (size_t)(ch * (BK / 2) + tp) * M_DIM);        // s_load (SGPRs)
      const u32 wv = wsh[buf][tp][lane];                     // ds_read_b32
      // strict k order per accumulator: all k0 updates, then all k1 updates
      pk_k0(acc[0], xv[0],  wv); pk_k0(acc[1], xv[2],  wv);
      pk_k0(acc[2], xv[4],  wv); pk_k0(acc[3], xv[6],  wv);
      pk_k0(acc[4], xv[8],  wv); pk_k0(acc[5], xv[10], wv);
      pk_k0(acc[6], xv[12], wv); pk_k0(acc[7], xv[14], wv);
      pk_k1(acc[0], xv[1],  wv); pk_k1(acc[1], xv[3],  wv);
      pk_k1(acc[2], xv[5],  wv); pk_k1(acc[3], xv[7],  wv);
      pk_k1(acc[4], xv[9],  wv); pk_k1(acc[5], xv[11], wv);
      pk_k1(acc[6], xv[13], wv); pk_k1(acc[7], xv[15], wv);
    }
  };

  stage(0, 0);
  __syncthreads();
#pragma unroll 1
  for (int ch = 0; ch < NCHUNK; ch += 2) {
    stage(ch + 1, 1);          // issue next chunk's loads before compute
    compute(ch, 0);
    __syncthreads();
    if (ch + 2 < NCHUNK) stage(ch + 2, 0);
    compute(ch + 1, 1);
    __syncthreads();
  }

  // epilogue: out = fp16RNE(acc + q8(b)), stored fp32 (fp32 add exact here).
  // acc[mp] half2 = rows {2mp, 2mp+1} at column nc -> same bias for both.
  const int nc = bn0 + lane;
  const float bq = quant_e4m3(b[nc]);
  float* orow = outp + (size_t)(bm0 + uw * 16) * N_DIM + nc;
#pragma unroll
  for (int mp = 0; mp < 8; mp++) {
    __half2 a = *reinterpret_cast<__half2*>(&acc[mp]);
    orow[(size_t)(2 * mp) * N_DIM]     = __half2float(__float2half(__low2float(a)  + bq));
    orow[(size_t)(2 * mp + 1) * N_DIM] = __half2float(__float2half(__high2float(a) + bq));
  }
}

extern "C" void kernel_launch(void* const* d_in, const int* in_sizes, int n_in,
                              void* d_out, int out_size, void* d_ws, size_t ws_size,
                              hipStream_t stream) {
  const float* x = (const float*)d_in[0];   // [2048][1024]
  const float* w = (const float*)d_in[1];   // [1024][1024] (out_f, in_f)
  const float* b = (const float*)d_in[2];   // [1024]
  float* outp = (float*)d_out;              // [2048][1024] fp32

  char* ws_ = (char*)d_ws;
  u32* xQ = (u32*)ws_;                        // [K/2][M] u32, 4 MiB
  u32* wK = (u32*)(ws_ + (size_t)(4 << 20));  // [K/2][N] u32, 2 MiB

  hipLaunchKernelGGL(prep_kernel, dim3(2048 + 1024), dim3(256), 0, stream,
                     x, w, xQ, wK);
  hipLaunchKernelGGL(gemm_qfma, dim3(N_DIM / BN, M_DIM / BM), dim3(256), 0, stream,
                     xQ, wK, b, outp);
}

// Round 9
// 145.844 us; speedup vs baseline: 1.4245x; 1.4245x over previous
//
#include <hip/hip_runtime.h>
#include <hip/hip_fp16.h>

// QLinear with per-k fp16 requantized accumulation (mptorch fma semantics).
// out = q16( q16_scan_fma( q8(x) @ q8(W)^T ) + q8(b) )
//
// Round-9: LDS-instruction economy via area-32 lane tile (8m x 4n).
// Measured law (R3/R7/R8): gemm time ~= total ds_read instr / 256 CU x ~12cyc,
// address-pattern independent. Area-32 cuts instr/MAC 1.33x:
// per k-pair: x 2x ds_read_b128 + w 1x ds_read_b128 feed 32 v_pk_fma_f16.
// 128-thr blocks (2 waves), grid 512, 2 blocks/CU. Prep layouts reused
// verbatim from round-7 (proven): xP[K/2][M] {k0,k1}-packed u32,
// wP[K/2][N] n-pair interleaved {k0 n01, k1 n01} u32 pairs.

#define M_DIM 2048
#define N_DIM 1024
#define K_DIM 1024

#define BM 32
#define BN 128
#define BK 64
#define NCHUNK (K_DIM / BK)   // 16

typedef unsigned u32;

// exact E4M3 (exp=4, man=3) quantization of an fp32 value, result fp32
__device__ __forceinline__ float quant_e4m3(float v) {
  unsigned au = __float_as_uint(v) & 0x7fffffffu;
  if (au == 0u) return v;                 // +-0
  int e = (int)(au >> 23) - 127;          // floor(log2|v|) for normals
  if (e < -6) e = -6;                     // fp32 subnorms hit the clamp too
  float s  = __uint_as_float((unsigned)(130 - e) << 23);  // 2^(3-e), exact
  float is = __uint_as_float((unsigned)(124 + e) << 23);  // 2^(e-3), exact
  float r = rintf(v * s) * is;            // RNE (half-to-even), all steps exact
  return fminf(240.f, fmaxf(-240.f, r));
}

// ---------- fused prep (identical to round-7, proven) ----------
// blocks [0,2048): x [M][K] -> xP[K/2][M], u32 = {q(x[m][2t]), q(x[m][2t+1])}
// blocks [2048,3072): w [N][K] -> wP[K/2][N/2][2] u32:
//   (t, np) -> { h2(q(w[2np][2t]),  q(w[2np+1][2t])),
//                h2(q(w[2np][2t+1]),q(w[2np+1][2t+1])) }
//   -> uint4 at col 4c covers {k0,k1} x n-pairs {2c,2c+1} (4 n, 2 k).
__global__ __launch_bounds__(256) void prep_kernel(const float* __restrict__ x,
                                                   const float* __restrict__ w,
                                                   u32* __restrict__ xP,
                                                   u32* __restrict__ wP) {
  __shared__ float tile[32][33];
  const int tx = threadIdx.x & 31;
  const int ty = threadIdx.x >> 5;
  if (blockIdx.x < 2048) {
    const int c0 = (blockIdx.x & 31) * 32;   // k offset
    const int r0 = (blockIdx.x >> 5) * 32;   // m offset
#pragma unroll
    for (int i = 0; i < 4; i++) {
      int r = r0 + ty + i * 8;
      tile[ty + i * 8][tx] = quant_e4m3(x[(size_t)r * K_DIM + c0 + tx]);
    }
    __syncthreads();
#pragma unroll
    for (int i = 0; i < 2; i++) {
      int tl = ty + i * 8;                   // k-pair local 0..15
      u32 lo = (u32)__half_as_ushort(__float2half(tile[tx][2 * tl]));
      u32 hi = (u32)__half_as_ushort(__float2half(tile[tx][2 * tl + 1]));
      xP[(size_t)(c0 / 2 + tl) * M_DIM + r0 + tx] = lo | (hi << 16);
    }
  } else {
    const int b = blockIdx.x - 2048;
    const int k0 = (b & 31) * 32;
    const int n0 = (b >> 5) * 32;
#pragma unroll
    for (int i = 0; i < 4; i++) {
      int n = n0 + ty + i * 8;
      tile[ty + i * 8][tx] = quant_e4m3(w[(size_t)n * K_DIM + k0 + tx]);  // [n_l][k_l]
    }
    __syncthreads();
    const int tpl = threadIdx.x >> 4;     // 0..15 k-pair local
    const int npl = threadIdx.x & 15;     // 0..15 n-pair local
    u32 a0 = (u32)__half_as_ushort(__float2half(tile[2 * npl][2 * tpl])) |
             ((u32)__half_as_ushort(__float2half(tile[2 * npl + 1][2 * tpl])) << 16);
    u32 a1 = (u32)__half_as_ushort(__float2half(tile[2 * npl][2 * tpl + 1])) |
             ((u32)__half_as_ushort(__float2half(tile[2 * npl + 1][2 * tpl + 1])) << 16);
    uint2 o; o.x = a0; o.y = a1;
    *reinterpret_cast<uint2*>(wP + (size_t)(k0 / 2 + tpl) * N_DIM + n0 + 2 * npl) = o;
  }
}

// ---------- GEMM ----------

__device__ __forceinline__ void gld16(const void* g, void* l) {
  __builtin_amdgcn_global_load_lds((const __attribute__((address_space(1))) u32*)g,
                                   (__attribute__((address_space(3))) u32*)l, 16, 0, 0);
}

// acc = pk_fma(splat(x.lo), w, acc)  -- k0 of the packed pair
__device__ __forceinline__ void pkfma_lo(u32& acc, u32 x, u32 w) {
  asm("v_pk_fma_f16 %0, %1, %2, %0 op_sel:[0,0,0] op_sel_hi:[0,1,1]"
      : "+v"(acc) : "v"(x), "v"(w));
}
// acc = pk_fma(splat(x.hi), w, acc)  -- k1 of the packed pair
__device__ __forceinline__ void pkfma_hi(u32& acc, u32 x, u32 w) {
  asm("v_pk_fma_f16 %0, %1, %2, %0 op_sel:[1,0,0] op_sel_hi:[1,1,1]"
      : "+v"(acc) : "v"(x), "v"(w));
}

// xP [K/2][M] u32, wP [K/2][N] u32 (n-pair interleaved), b [N] fp32,
// out [M][N] fp32.  128 threads = 2 waves; block tile 32m x 128n;
// lane tile 8m x 4n: tn = tid&31 (4n each), tm = tid>>5 (8m each).
__global__ __launch_bounds__(128, 2) void gemm_qfma(const u32* __restrict__ xP,
                                                    const u32* __restrict__ wP,
                                                    const float* __restrict__ b,
                                                    float* __restrict__ outp) {
  __shared__ __align__(16) u32 xs[2][BK / 2][BM];    // 2 x 32 x 32 u32  =  8 KB
  __shared__ __align__(16) u32 wsh[2][BK / 2][BN];   // 2 x 32 x 128 u32 = 32 KB
  const int tid = threadIdx.x;
  const int tn = tid & 31;          // n-group: cols 4tn..4tn+3
  const int tm = tid >> 5;          // m-group: rows 8tm..8tm+7
  const int bn0 = blockIdx.x * BN;
  const int bm0 = blockIdx.y * BM;

  u32 acc[8][2];                    // [m-row][n-pair]
#pragma unroll
  for (int i = 0; i < 8; i++) { acc[i][0] = 0u; acc[i][1] = 0u; }

  // staging: linear LDS (wave-uniform base + lane*16), per-lane global src.
  // x: 32 rows x 32 u32 = 4 KB = 2 passes x 128 thr x 16 B
  // w: 32 rows x 128 u32 = 16 KB = 8 passes
  const u32* xsrc = xP + (size_t)(tid >> 3) * M_DIM + bm0 + ((tid & 7) << 2);
  const u32* wsrc = wP + (size_t)(tid >> 5) * N_DIM + bn0 + ((tid & 31) << 2);

  auto stage = [&](int ch, int buf) {
    const u32* xp = xsrc + (size_t)ch * (BK / 2) * M_DIM;
    char* xl = (char*)&xs[buf][0][0] + tid * 16;
    gld16(xp, xl);                                   // rows 0..15
    gld16(xp + (size_t)16 * M_DIM, xl + 2048);       // rows 16..31
    const u32* wp = wsrc + (size_t)ch * (BK / 2) * N_DIM;
    char* wl = (char*)&wsh[buf][0][0] + tid * 16;
#pragma unroll
    for (int p = 0; p < 8; p++)
      gld16(wp + (size_t)(p * 4) * N_DIM, wl + p * 2048);
  };

  auto compute = [&](int buf) {
#pragma unroll
    for (int tp = 0; tp < BK / 2; tp++) {   // k-pair: k0=2tp, k1=2tp+1
      u32 xm[8];
      *reinterpret_cast<uint4*>(&xm[0]) =
          *reinterpret_cast<const uint4*>(&xs[buf][tp][tm << 3]);
      *reinterpret_cast<uint4*>(&xm[4]) =
          *reinterpret_cast<const uint4*>(&xs[buf][tp][(tm << 3) + 4]);
      const uint4 wv = *reinterpret_cast<const uint4*>(&wsh[buf][tp][tn << 2]);
      // wv = {k0 n01, k1 n01, k0 n23, k1 n23}
      // strict k order per accumulator: all k0 updates, then all k1 updates
#pragma unroll
      for (int i = 0; i < 8; i++) {
        pkfma_lo(acc[i][0], xm[i], wv.x);
        pkfma_lo(acc[i][1], xm[i], wv.z);
      }
#pragma unroll
      for (int i = 0; i < 8; i++) {
        pkfma_hi(acc[i][0], xm[i], wv.y);
        pkfma_hi(acc[i][1], xm[i], wv.w);
      }
    }
  };

  stage(0, 0);
  __syncthreads();
#pragma unroll 1
  for (int ch = 0; ch < NCHUNK; ch += 2) {
    stage(ch + 1, 1);          // issue next chunk's loads before compute
    compute(0);
    __syncthreads();
    if (ch + 2 < NCHUNK) stage(ch + 2, 0);
    compute(1);
    __syncthreads();
  }

  // epilogue: out = fp16RNE(acc + q8(b)), stored fp32 (fp32 add exact here)
  const int nc = bn0 + (tn << 2);
  float4 bq;
  bq.x = quant_e4m3(b[nc + 0]);
  bq.y = quant_e4m3(b[nc + 1]);
  bq.z = quant_e4m3(b[nc + 2]);
  bq.w = quant_e4m3(b[nc + 3]);
#pragma unroll
  for (int i = 0; i < 8; i++) {
    __half2 a0 = *reinterpret_cast<__half2*>(&acc[i][0]);  // n0,n1
    __half2 a1 = *reinterpret_cast<__half2*>(&acc[i][1]);  // n2,n3
    float4 o;
    o.x = __half2float(__float2half(__low2float(a0)  + bq.x));
    o.y = __half2float(__float2half(__high2float(a0) + bq.y));
    o.z = __half2float(__float2half(__low2float(a1)  + bq.z));
    o.w = __half2float(__float2half(__high2float(a1) + bq.w));
    *reinterpret_cast<float4*>(
        outp + (size_t)(bm0 + (tm << 3) + i) * N_DIM + nc) = o;
  }
}

extern "C" void kernel_launch(void* const* d_in, const int* in_sizes, int n_in,
                              void* d_out, int out_size, void* d_ws, size_t ws_size,
                              hipStream_t stream) {
  const float* x = (const float*)d_in[0];   // [2048][1024]
  const float* w = (const float*)d_in[1];   // [1024][1024] (out_f, in_f)
  const float* b = (const float*)d_in[2];   // [1024]
  float* outp = (float*)d_out;              // [2048][1024] fp32

  char* ws_ = (char*)d_ws;
  u32* xP = (u32*)ws_;                        // [K/2][M] u32, 4 MiB
  u32* wP = (u32*)(ws_ + (size_t)(4 << 20));  // [K/2][N] u32, 2 MiB

  hipLaunchKernelGGL(prep_kernel, dim3(2048 + 1024), dim3(256), 0, stream,
                     x, w, xP, wP);
  hipLaunchKernelGGL(gemm_qfma, dim3(N_DIM / BN, M_DIM / BM), dim3(128), 0, stream,
                     xP, wP, b, outp);
}

// Round 10
// 136.623 us; speedup vs baseline: 1.5207x; 1.0675x over previous
//
#include <hip/hip_runtime.h>
#include <hip/hip_fp16.h>

// QLinear with per-k fp16 requantized accumulation (mptorch fma semantics).
// out = q16( q16_scan_fma( q8(x) @ q8(W)^T ) + q8(b) )
//
// Round-10: operands stored as E4M3 BYTES in LDS (8-bit), expanded in-register
// via gfx950 hw decode. Per k-QUAD (4 k) per lane: 1 ds_read_b128 x (4m x 4k
// bytes) + 1 ds_read_b128 w (4n x 4k bytes) -> LDS instr/k-pair halves vs R3.
// Decode: cvt_pk_f32_fp8 (OCP e4m3fn on gfx950; all quant values exactly
// representable, max 240 < 448, same emin/subnorm scale) + v_cvt_pkrtz
// (values exact in fp16 -> RTZ never rounds). pk_fma stream bit-identical
// to round-3 (passed, absmax 0.03125). Geometry: R3's proven 256 thr,
// BM32 x BN128, lane 4m x 4n, 8 waves/CU, gld16 double-buffer.

#define M_DIM 2048
#define N_DIM 1024
#define K_DIM 1024

#define BM 32
#define BN 128
#define BK 64
#define NCHUNK (K_DIM / BK)   // 16

typedef unsigned u32;
typedef float f32x2 __attribute__((ext_vector_type(2)));

// exact E4M3 (exp=4, man=3) quantization of an fp32 value, result fp32
__device__ __forceinline__ float quant_e4m3(float v) {
  unsigned au = __float_as_uint(v) & 0x7fffffffu;
  if (au == 0u) return v;                 // +-0
  int e = (int)(au >> 23) - 127;          // floor(log2|v|) for normals
  if (e < -6) e = -6;                     // fp32 subnorms hit the clamp too
  float s  = __uint_as_float((unsigned)(130 - e) << 23);  // 2^(3-e), exact
  float is = __uint_as_float((unsigned)(124 + e) << 23);  // 2^(e-3), exact
  float r = rintf(v * s) * is;            // RNE (half-to-even), all steps exact
  return fminf(240.f, fmaxf(-240.f, r));
}

// exact encode of an E4M3-representable fp32 value to an OCP e4m3fn byte.
// inputs are quant_e4m3 outputs: 0, or man(4b incl implicit) x 2^(e-3),
// e in [-9..7], |v| <= 240. All cases exactly encodable.
__device__ __forceinline__ u32 enc_e4m3(float v) {
  unsigned au = __float_as_uint(v);
  unsigned sg = (au >> 24) & 0x80u;
  unsigned a = au & 0x7fffffffu;
  if (a == 0u) return sg;                 // +-0
  int e = (int)(a >> 23) - 127;           // value is f32-normal (>= 2^-9)
  unsigned man = (a >> 20) & 7u;
  if (e >= -6) return sg | ((unsigned)(e + 7) << 3) | man;   // normal
  return sg | ((8u | man) >> (-6 - e));   // subnormal: multiples of 2^-9
}

// ---------- fused prep ----------
// blocks [0,2048): x [M][K] -> xB u32[K/4][M]; u32(m) = bytes
//   { e(x[m][4q]), e(x[m][4q+1]), e(x[m][4q+2]), e(x[m][4q+3]) }
// blocks [2048,3072): w [N][K] -> wB u32[K/4][N] viewed as uint4[K/4][N/4];
//   entry (q, c) = { u32{n0k0,n1k0,n0k1,n1k1}, u32{n2k0,n3k0,n2k1,n3k1},
//                    u32{n0k2,n1k2,n0k3,n1k3}, u32{n2k2,n3k2,n2k3,n3k3} }
//   with n_i = 4c+i, k_j = 4q+j  (byte0 = lowest -> cvt pair order)
__global__ __launch_bounds__(256) void prep_kernel(const float* __restrict__ x,
                                                   const float* __restrict__ w,
                                                   u32* __restrict__ xB,
                                                   u32* __restrict__ wB) {
  __shared__ float tile[32][33];
  const int tx = threadIdx.x & 31;
  const int ty = threadIdx.x >> 5;
  if (blockIdx.x < 2048) {
    const int c0 = (blockIdx.x & 31) * 32;   // k offset
    const int r0 = (blockIdx.x >> 5) * 32;   // m offset
#pragma unroll
    for (int i = 0; i < 4; i++) {
      int r = r0 + ty + i * 8;
      tile[ty + i * 8][tx] = quant_e4m3(x[(size_t)r * K_DIM + c0 + tx]);  // [m_l][k_l]
    }
    __syncthreads();
    const int ml = tx;                    // 0..31 m local
    const int ql = ty;                    // 0..7  k-quad local
    u32 v = enc_e4m3(tile[ml][4 * ql + 0])
          | (enc_e4m3(tile[ml][4 * ql + 1]) << 8)
          | (enc_e4m3(tile[ml][4 * ql + 2]) << 16)
          | (enc_e4m3(tile[ml][4 * ql + 3]) << 24);
    xB[(size_t)(c0 / 4 + ql) * M_DIM + r0 + ml] = v;
  } else {
    const int b = blockIdx.x - 2048;
    const int k0t = (b & 31) * 32;
    const int n0t = (b >> 5) * 32;
#pragma unroll
    for (int i = 0; i < 4; i++) {
      int n = n0t + ty + i * 8;
      tile[ty + i * 8][tx] = quant_e4m3(w[(size_t)n * K_DIM + k0t + tx]);  // [n_l][k_l]
    }
    __syncthreads();
    const int u = threadIdx.x & 3;        // u32 slot in uint4
    const int cl = (threadIdx.x >> 2) & 7;  // n-chunk local (4 n)
    const int ql = (threadIdx.x >> 5) & 7;  // k-quad local
    const int nl = 4 * cl + 2 * (u & 1);    // n base for this u32
    const int kl = 4 * ql + 2 * (u >> 1);   // k base for this u32
    u32 v = enc_e4m3(tile[nl][kl])
          | (enc_e4m3(tile[nl + 1][kl]) << 8)
          | (enc_e4m3(tile[nl][kl + 1]) << 16)
          | (enc_e4m3(tile[nl + 1][kl + 1]) << 24);
    wB[(size_t)(k0t / 4 + ql) * N_DIM + n0t + (cl << 2) + u] = v;
  }
}

// ---------- GEMM ----------

__device__ __forceinline__ void gld16(const void* g, void* l) {
  __builtin_amdgcn_global_load_lds((const __attribute__((address_space(1))) u32*)g,
                                   (__attribute__((address_space(3))) u32*)l, 16, 0, 0);
}

// decode one fp8 byte-pair (word HI of v) to packed fp16 pair {b0, b1}.
// exact: e4m3fn -> f32 (hw) -> f16 (values subset of fp16; RTZ never rounds)
template <int HI>
__device__ __forceinline__ u32 fp8x2_h2(u32 v) {
  f32x2 f = __builtin_amdgcn_cvt_pk_f32_fp8((int)v, HI);
  u32 r;
  asm("v_cvt_pkrtz_f16_f32 %0, %1, %2" : "=v"(r) : "v"(f[0]), "v"(f[1]));
  return r;
}

// acc = pk_fma(splat(x.lo), w, acc)  -- first k of the pair
__device__ __forceinline__ void pkfma_lo(u32& acc, u32 x, u32 w) {
  asm("v_pk_fma_f16 %0, %1, %2, %0 op_sel:[0,0,0] op_sel_hi:[0,1,1]"
      : "+v"(acc) : "v"(x), "v"(w));
}
// acc = pk_fma(splat(x.hi), w, acc)  -- second k of the pair
__device__ __forceinline__ void pkfma_hi(u32& acc, u32 x, u32 w) {
  asm("v_pk_fma_f16 %0, %1, %2, %0 op_sel:[1,0,0] op_sel_hi:[1,1,1]"
      : "+v"(acc) : "v"(x), "v"(w));
}

// xB u32[K/4][M] bytes, wB u32[K/4][N] (uint4-grouped), b [N] fp32,
// out [M][N] fp32.  256 threads; tile 32m x 128n; lane 4m x 4n;
// tn = tid&31 (n-group), tm = tid>>5 (m-group).
__global__ __launch_bounds__(256, 2) void gemm_qfma(const u32* __restrict__ xB,
                                                    const u32* __restrict__ wB,
                                                    const float* __restrict__ b,
                                                    float* __restrict__ outp) {
  __shared__ __align__(16) u32 xs[2][BK / 4][BM];    // 2 x 16 x 32 u32  =  4 KB
  __shared__ __align__(16) u32 wsu[2][BK / 4][BN];   // 2 x 16 x 128 u32 = 16 KB
  const int tid = threadIdx.x;
  const int tn = tid & 31;
  const int tm = tid >> 5;
  const int bn0 = blockIdx.x * BN;
  const int bm0 = blockIdx.y * BM;

  u32 acc[4][2];
#pragma unroll
  for (int i = 0; i < 4; i++) { acc[i][0] = 0u; acc[i][1] = 0u; }

  // staging: linear LDS (base + tid*16), per-lane global src.
  // x: 16 rows x 32 u32 = 2 KB -> 128 threads x 16 B (waves 0,1 only)
  // w: 16 rows x 128 u32 = 8 KB -> 256 threads x 2 x 16 B
  const u32* xsrc = xB + (size_t)(tid >> 3) * M_DIM + bm0 + ((tid & 7) << 2);
  const u32* wsrc = wB + (size_t)(tid >> 5) * N_DIM + bn0 + ((tid & 31) << 2);

  auto stage = [&](int ch, int buf) {
    if (tid < 128) {   // wave-uniform branch (waves 0,1)
      gld16(xsrc + (size_t)ch * (BK / 4) * M_DIM, (char*)&xs[buf][0][0] + tid * 16);
    }
    const u32* wp = wsrc + (size_t)ch * (BK / 4) * N_DIM;
    char* wl = (char*)&wsu[buf][0][0] + tid * 16;
    gld16(wp, wl);                                   // rows 0..7
    gld16(wp + (size_t)8 * N_DIM, wl + 4096);        // rows 8..15
  };

  auto compute = [&](int buf) {
#pragma unroll
    for (int q = 0; q < BK / 4; q++) {      // k-quad: k = 4q .. 4q+3
      const uint4 xq = *reinterpret_cast<const uint4*>(&xs[buf][q][tm << 2]);
      const uint4 wq = *reinterpret_cast<const uint4*>(&wsu[buf][q][tn << 2]);
      // ---- k-pair (4q, 4q+1): x sel0, w from wq.x / wq.y ----
      {
        const u32 x0 = fp8x2_h2<0>(xq.x), x1 = fp8x2_h2<0>(xq.y);
        const u32 x2 = fp8x2_h2<0>(xq.z), x3 = fp8x2_h2<0>(xq.w);
        const u32 wk0a = fp8x2_h2<0>(wq.x);   // k0: n01
        const u32 wk1a = fp8x2_h2<1>(wq.x);   // k1: n01
        const u32 wk0b = fp8x2_h2<0>(wq.y);   // k0: n23
        const u32 wk1b = fp8x2_h2<1>(wq.y);   // k1: n23
        // strict k order per accumulator: all k0, then all k1
        pkfma_lo(acc[0][0], x0, wk0a); pkfma_lo(acc[0][1], x0, wk0b);
        pkfma_lo(acc[1][0], x1, wk0a); pkfma_lo(acc[1][1], x1, wk0b);
        pkfma_lo(acc[2][0], x2, wk0a); pkfma_lo(acc[2][1], x2, wk0b);
        pkfma_lo(acc[3][0], x3, wk0a); pkfma_lo(acc[3][1], x3, wk0b);
        pkfma_hi(acc[0][0], x0, wk1a); pkfma_hi(acc[0][1], x0, wk1b);
        pkfma_hi(acc[1][0], x1, wk1a); pkfma_hi(acc[1][1], x1, wk1b);
        pkfma_hi(acc[2][0], x2, wk1a); pkfma_hi(acc[2][1], x2, wk1b);
        pkfma_hi(acc[3][0], x3, wk1a); pkfma_hi(acc[3][1], x3, wk1b);
      }
      // ---- k-pair (4q+2, 4q+3): x sel1, w from wq.z / wq.w ----
      {
        const u32 x0 = fp8x2_h2<1>(xq.x), x1 = fp8x2_h2<1>(xq.y);
        const u32 x2 = fp8x2_h2<1>(xq.z), x3 = fp8x2_h2<1>(xq.w);
        const u32 wk2a = fp8x2_h2<0>(wq.z);   // k2: n01
        const u32 wk3a = fp8x2_h2<1>(wq.z);   // k3: n01
        const u32 wk2b = fp8x2_h2<0>(wq.w);   // k2: n23
        const u32 wk3b = fp8x2_h2<1>(wq.w);   // k3: n23
        pkfma_lo(acc[0][0], x0, wk2a); pkfma_lo(acc[0][1], x0, wk2b);
        pkfma_lo(acc[1][0], x1, wk2a); pkfma_lo(acc[1][1], x1, wk2b);
        pkfma_lo(acc[2][0], x2, wk2a); pkfma_lo(acc[2][1], x2, wk2b);
        pkfma_lo(acc[3][0], x3, wk2a); pkfma_lo(acc[3][1], x3, wk2b);
        pkfma_hi(acc[0][0], x0, wk3a); pkfma_hi(acc[0][1], x0, wk3b);
        pkfma_hi(acc[1][0], x1, wk3a); pkfma_hi(acc[1][1], x1, wk3b);
        pkfma_hi(acc[2][0], x2, wk3a); pkfma_hi(acc[2][1], x2, wk3b);
        pkfma_hi(acc[3][0], x3, wk3a); pkfma_hi(acc[3][1], x3, wk3b);
      }
    }
  };

  stage(0, 0);
  __syncthreads();
#pragma unroll 1
  for (int ch = 0; ch < NCHUNK; ch += 2) {
    stage(ch + 1, 1);          // issue next chunk's loads before compute
    compute(0);
    __syncthreads();
    if (ch + 2 < NCHUNK) stage(ch + 2, 0);
    compute(1);
    __syncthreads();
  }

  // epilogue: out = fp16RNE(acc + q8(b)), stored fp32 (fp32 add exact here)
  const int nc = bn0 + (tn << 2);
  float4 bq;
  bq.x = quant_e4m3(b[nc + 0]);
  bq.y = quant_e4m3(b[nc + 1]);
  bq.z = quant_e4m3(b[nc + 2]);
  bq.w = quant_e4m3(b[nc + 3]);
#pragma unroll
  for (int i = 0; i < 4; i++) {
    __half2 a0 = *reinterpret_cast<__half2*>(&acc[i][0]);  // n0,n1
    __half2 a1 = *reinterpret_cast<__half2*>(&acc[i][1]);  // n2,n3
    float4 o;
    o.x = __half2float(__float2half(__low2float(a0)  + bq.x));
    o.y = __half2float(__float2half(__high2float(a0) + bq.y));
    o.z = __half2float(__float2half(__low2float(a1)  + bq.z));
    o.w = __half2float(__float2half(__high2float(a1) + bq.w));
    *reinterpret_cast<float4*>(
        outp + (size_t)(bm0 + (tm << 2) + i) * N_DIM + nc) = o;
  }
}

extern "C" void kernel_launch(void* const* d_in, const int* in_sizes, int n_in,
                              void* d_out, int out_size, void* d_ws, size_t ws_size,
                              hipStream_t stream) {
  const float* x = (const float*)d_in[0];   // [2048][1024]
  const float* w = (const float*)d_in[1];   // [1024][1024] (out_f, in_f)
  const float* b = (const float*)d_in[2];   // [1024]
  float* outp = (float*)d_out;              // [2048][1024] fp32

  char* ws_ = (char*)d_ws;
  u32* xB = (u32*)ws_;                        // [K/4][M] u32 bytes, 2 MiB
  u32* wB = (u32*)(ws_ + (size_t)(2 << 20));  // [K/4][N] u32 bytes, 1 MiB

  hipLaunchKernelGGL(prep_kernel, dim3(2048 + 1024), dim3(256), 0, stream,
                     x, w, xB, wB);
  hipLaunchKernelGGL(gemm_qfma, dim3(N_DIM / BN, M_DIM / BM), dim3(256), 0, stream,
                     xB, wB, b, outp);
}

// Round 11
// 121.812 us; speedup vs baseline: 1.7055x; 1.1216x over previous
//
#include <hip/hip_runtime.h>
#include <hip/hip_fp16.h>

// QLinear with per-k fp16 requantized accumulation (mptorch fma semantics).
// out = q16( q16_scan_fma( q8(x) @ q8(W)^T ) + q8(b) )
//
// Round-11: round-10 (fp8 bytes in LDS, 2 ds_read_b128 per k-quad) with the
// decode halved: v_cvt_scalef32_pk_f16_fp8 converts an fp8 byte-pair to
// packed f16 in ONE instruction (scale=1.0 exact; e4m3fn -> f16 value-exact
// incl. subnormals -- it's the hw MX dequant path). Per k-quad per wave:
// 16 decode + 32 pk_fma = 48 VALU (~192 cyc/SIMD at 2 waves) balanced
// against LDS 192 cyc/CU. Fallback (builtin absent): round-10's 2-instr
// decode. All layouts / staging / fma chain identical to round-10 (passed).

#define M_DIM 2048
#define N_DIM 1024
#define K_DIM 1024

#define BM 32
#define BN 128
#define BK 64
#define NCHUNK (K_DIM / BK)   // 16

typedef unsigned u32;
typedef float f32x2 __attribute__((ext_vector_type(2)));
typedef _Float16 f16x2 __attribute__((ext_vector_type(2)));

// exact E4M3 (exp=4, man=3) quantization of an fp32 value, result fp32
__device__ __forceinline__ float quant_e4m3(float v) {
  unsigned au = __float_as_uint(v) & 0x7fffffffu;
  if (au == 0u) return v;                 // +-0
  int e = (int)(au >> 23) - 127;          // floor(log2|v|) for normals
  if (e < -6) e = -6;                     // fp32 subnorms hit the clamp too
  float s  = __uint_as_float((unsigned)(130 - e) << 23);  // 2^(3-e), exact
  float is = __uint_as_float((unsigned)(124 + e) << 23);  // 2^(e-3), exact
  float r = rintf(v * s) * is;            // RNE (half-to-even), all steps exact
  return fminf(240.f, fmaxf(-240.f, r));
}

// exact encode of an E4M3-representable fp32 value to an OCP e4m3fn byte.
__device__ __forceinline__ u32 enc_e4m3(float v) {
  unsigned au = __float_as_uint(v);
  unsigned sg = (au >> 24) & 0x80u;
  unsigned a = au & 0x7fffffffu;
  if (a == 0u) return sg;                 // +-0
  int e = (int)(a >> 23) - 127;           // value is f32-normal (>= 2^-9)
  unsigned man = (a >> 20) & 7u;
  if (e >= -6) return sg | ((unsigned)(e + 7) << 3) | man;   // normal
  return sg | ((8u | man) >> (-6 - e));   // subnormal: multiples of 2^-9
}

// ---------- fused prep (identical to round-10, proven) ----------
// blocks [0,2048): x [M][K] -> xB u32[K/4][M]; u32(m) = bytes
//   { e(x[m][4q]), e(x[m][4q+1]), e(x[m][4q+2]), e(x[m][4q+3]) }
// blocks [2048,3072): w [N][K] -> wB u32[K/4][N] viewed as uint4[K/4][N/4];
//   entry (q, c) = { u32{n0k0,n1k0,n0k1,n1k1}, u32{n2k0,n3k0,n2k1,n3k1},
//                    u32{n0k2,n1k2,n0k3,n1k3}, u32{n2k2,n3k2,n2k3,n3k3} }
__global__ __launch_bounds__(256) void prep_kernel(const float* __restrict__ x,
                                                   const float* __restrict__ w,
                                                   u32* __restrict__ xB,
                                                   u32* __restrict__ wB) {
  __shared__ float tile[32][33];
  const int tx = threadIdx.x & 31;
  const int ty = threadIdx.x >> 5;
  if (blockIdx.x < 2048) {
    const int c0 = (blockIdx.x & 31) * 32;   // k offset
    const int r0 = (blockIdx.x >> 5) * 32;   // m offset
#pragma unroll
    for (int i = 0; i < 4; i++) {
      int r = r0 + ty + i * 8;
      tile[ty + i * 8][tx] = quant_e4m3(x[(size_t)r * K_DIM + c0 + tx]);  // [m_l][k_l]
    }
    __syncthreads();
    const int ml = tx;                    // 0..31 m local
    const int ql = ty;                    // 0..7  k-quad local
    u32 v = enc_e4m3(tile[ml][4 * ql + 0])
          | (enc_e4m3(tile[ml][4 * ql + 1]) << 8)
          | (enc_e4m3(tile[ml][4 * ql + 2]) << 16)
          | (enc_e4m3(tile[ml][4 * ql + 3]) << 24);
    xB[(size_t)(c0 / 4 + ql) * M_DIM + r0 + ml] = v;
  } else {
    const int b = blockIdx.x - 2048;
    const int k0t = (b & 31) * 32;
    const int n0t = (b >> 5) * 32;
#pragma unroll
    for (int i = 0; i < 4; i++) {
      int n = n0t + ty + i * 8;
      tile[ty + i * 8][tx] = quant_e4m3(w[(size_t)n * K_DIM + k0t + tx]);  // [n_l][k_l]
    }
    __syncthreads();
    const int u = threadIdx.x & 3;        // u32 slot in uint4
    const int cl = (threadIdx.x >> 2) & 7;  // n-chunk local (4 n)
    const int ql = (threadIdx.x >> 5) & 7;  // k-quad local
    const int nl = 4 * cl + 2 * (u & 1);    // n base for this u32
    const int kl = 4 * ql + 2 * (u >> 1);   // k base for this u32
    u32 v = enc_e4m3(tile[nl][kl])
          | (enc_e4m3(tile[nl + 1][kl]) << 8)
          | (enc_e4m3(tile[nl][kl + 1]) << 16)
          | (enc_e4m3(tile[nl + 1][kl + 1]) << 24);
    wB[(size_t)(k0t / 4 + ql) * N_DIM + n0t + (cl << 2) + u] = v;
  }
}

// ---------- GEMM ----------

__device__ __forceinline__ void gld16(const void* g, void* l) {
  __builtin_amdgcn_global_load_lds((const __attribute__((address_space(1))) u32*)g,
                                   (__attribute__((address_space(3))) u32*)l, 16, 0, 0);
}

// decode one fp8 byte-pair (word HI of v) to packed fp16 pair {b0, b1}.
// exact: e4m3fn values are a subset of fp16; scale 1.0 is identity.
#if __has_builtin(__builtin_amdgcn_cvt_scalef32_pk_f16_fp8)
template <int HI>
__device__ __forceinline__ u32 fp8x2_h2(u32 v) {
  f16x2 h = __builtin_amdgcn_cvt_scalef32_pk_f16_fp8((int)v, 1.0f, HI != 0);
  return __builtin_bit_cast(u32, h);      // 1 VALU instr per 2 values
}
#else
template <int HI>
__device__ __forceinline__ u32 fp8x2_h2(u32 v) {
  f32x2 f = __builtin_amdgcn_cvt_pk_f32_fp8((int)v, HI);
  u32 r;
  asm("v_cvt_pkrtz_f16_f32 %0, %1, %2" : "=v"(r) : "v"(f[0]), "v"(f[1]));
  return r;                               // 2 VALU instr per 2 values
}
#endif

// acc = pk_fma(splat(x.lo), w, acc)  -- first k of the pair
__device__ __forceinline__ void pkfma_lo(u32& acc, u32 x, u32 w) {
  asm("v_pk_fma_f16 %0, %1, %2, %0 op_sel:[0,0,0] op_sel_hi:[0,1,1]"
      : "+v"(acc) : "v"(x), "v"(w));
}
// acc = pk_fma(splat(x.hi), w, acc)  -- second k of the pair
__device__ __forceinline__ void pkfma_hi(u32& acc, u32 x, u32 w) {
  asm("v_pk_fma_f16 %0, %1, %2, %0 op_sel:[1,0,0] op_sel_hi:[1,1,1]"
      : "+v"(acc) : "v"(x), "v"(w));
}

// xB u32[K/4][M] bytes, wB u32[K/4][N] (uint4-grouped), b [N] fp32,
// out [M][N] fp32.  256 threads; tile 32m x 128n; lane 4m x 4n.
__global__ __launch_bounds__(256, 2) void gemm_qfma(const u32* __restrict__ xB,
                                                    const u32* __restrict__ wB,
                                                    const float* __restrict__ b,
                                                    float* __restrict__ outp) {
  __shared__ __align__(16) u32 xs[2][BK / 4][BM];    // 2 x 16 x 32 u32  =  4 KB
  __shared__ __align__(16) u32 wsu[2][BK / 4][BN];   // 2 x 16 x 128 u32 = 16 KB
  const int tid = threadIdx.x;
  const int tn = tid & 31;
  const int tm = tid >> 5;
  const int bn0 = blockIdx.x * BN;
  const int bm0 = blockIdx.y * BM;

  u32 acc[4][2];
#pragma unroll
  for (int i = 0; i < 4; i++) { acc[i][0] = 0u; acc[i][1] = 0u; }

  // staging: linear LDS (base + tid*16), per-lane global src.
  const u32* xsrc = xB + (size_t)(tid >> 3) * M_DIM + bm0 + ((tid & 7) << 2);
  const u32* wsrc = wB + (size_t)(tid >> 5) * N_DIM + bn0 + ((tid & 31) << 2);

  auto stage = [&](int ch, int buf) {
    if (tid < 128) {   // wave-uniform branch (waves 0,1)
      gld16(xsrc + (size_t)ch * (BK / 4) * M_DIM, (char*)&xs[buf][0][0] + tid * 16);
    }
    const u32* wp = wsrc + (size_t)ch * (BK / 4) * N_DIM;
    char* wl = (char*)&wsu[buf][0][0] + tid * 16;
    gld16(wp, wl);                                   // rows 0..7
    gld16(wp + (size_t)8 * N_DIM, wl + 4096);        // rows 8..15
  };

  auto compute = [&](int buf) {
#pragma unroll
    for (int q = 0; q < BK / 4; q++) {      // k-quad: k = 4q .. 4q+3
      const uint4 xq = *reinterpret_cast<const uint4*>(&xs[buf][q][tm << 2]);
      const uint4 wq = *reinterpret_cast<const uint4*>(&wsu[buf][q][tn << 2]);
      // ---- k-pair (4q, 4q+1): x sel0, w from wq.x / wq.y ----
      {
        const u32 x0 = fp8x2_h2<0>(xq.x), x1 = fp8x2_h2<0>(xq.y);
        const u32 x2 = fp8x2_h2<0>(xq.z), x3 = fp8x2_h2<0>(xq.w);
        const u32 wk0a = fp8x2_h2<0>(wq.x);   // k0: n01
        const u32 wk1a = fp8x2_h2<1>(wq.x);   // k1: n01
        const u32 wk0b = fp8x2_h2<0>(wq.y);   // k0: n23
        const u32 wk1b = fp8x2_h2<1>(wq.y);   // k1: n23
        // strict k order per accumulator: all k0, then all k1
        pkfma_lo(acc[0][0], x0, wk0a); pkfma_lo(acc[0][1], x0, wk0b);
        pkfma_lo(acc[1][0], x1, wk0a); pkfma_lo(acc[1][1], x1, wk0b);
        pkfma_lo(acc[2][0], x2, wk0a); pkfma_lo(acc[2][1], x2, wk0b);
        pkfma_lo(acc[3][0], x3, wk0a); pkfma_lo(acc[3][1], x3, wk0b);
        pkfma_hi(acc[0][0], x0, wk1a); pkfma_hi(acc[0][1], x0, wk1b);
        pkfma_hi(acc[1][0], x1, wk1a); pkfma_hi(acc[1][1], x1, wk1b);
        pkfma_hi(acc[2][0], x2, wk1a); pkfma_hi(acc[2][1], x2, wk1b);
        pkfma_hi(acc[3][0], x3, wk1a); pkfma_hi(acc[3][1], x3, wk1b);
      }
      // ---- k-pair (4q+2, 4q+3): x sel1, w from wq.z / wq.w ----
      {
        const u32 x0 = fp8x2_h2<1>(xq.x), x1 = fp8x2_h2<1>(xq.y);
        const u32 x2 = fp8x2_h2<1>(xq.z), x3 = fp8x2_h2<1>(xq.w);
        const u32 wk2a = fp8x2_h2<0>(wq.z);   // k2: n01
        const u32 wk3a = fp8x2_h2<1>(wq.z);   // k3: n01
        const u32 wk2b = fp8x2_h2<0>(wq.w);   // k2: n23
        const u32 wk3b = fp8x2_h2<1>(wq.w);   // k3: n23
        pkfma_lo(acc[0][0], x0, wk2a); pkfma_lo(acc[0][1], x0, wk2b);
        pkfma_lo(acc[1][0], x1, wk2a); pkfma_lo(acc[1][1], x1, wk2b);
        pkfma_lo(acc[2][0], x2, wk2a); pkfma_lo(acc[2][1], x2, wk2b);
        pkfma_lo(acc[3][0], x3, wk2a); pkfma_lo(acc[3][1], x3, wk2b);
        pkfma_hi(acc[0][0], x0, wk3a); pkfma_hi(acc[0][1], x0, wk3b);
        pkfma_hi(acc[1][0], x1, wk3a); pkfma_hi(acc[1][1], x1, wk3b);
        pkfma_hi(acc[2][0], x2, wk3a); pkfma_hi(acc[2][1], x2, wk3b);
        pkfma_hi(acc[3][0], x3, wk3a); pkfma_hi(acc[3][1], x3, wk3b);
      }
    }
  };

  stage(0, 0);
  __syncthreads();
#pragma unroll 1
  for (int ch = 0; ch < NCHUNK; ch += 2) {
    stage(ch + 1, 1);          // issue next chunk's loads before compute
    compute(0);
    __syncthreads();
    if (ch + 2 < NCHUNK) stage(ch + 2, 0);
    compute(1);
    __syncthreads();
  }

  // epilogue: out = fp16RNE(acc + q8(b)), stored fp32 (fp32 add exact here)
  const int nc = bn0 + (tn << 2);
  float4 bq;
  bq.x = quant_e4m3(b[nc + 0]);
  bq.y = quant_e4m3(b[nc + 1]);
  bq.z = quant_e4m3(b[nc + 2]);
  bq.w = quant_e4m3(b[nc + 3]);
#pragma unroll
  for (int i = 0; i < 4; i++) {
    __half2 a0 = *reinterpret_cast<__half2*>(&acc[i][0]);  // n0,n1
    __half2 a1 = *reinterpret_cast<__half2*>(&acc[i][1]);  // n2,n3
    float4 o;
    o.x = __half2float(__float2half(__low2float(a0)  + bq.x));
    o.y = __half2float(__float2half(__high2float(a0) + bq.y));
    o.z = __half2float(__float2half(__low2float(a1)  + bq.z));
    o.w = __half2float(__float2half(__high2float(a1) + bq.w));
    *reinterpret_cast<float4*>(
        outp + (size_t)(bm0 + (tm << 2) + i) * N_DIM + nc) = o;
  }
}

extern "C" void kernel_launch(void* const* d_in, const int* in_sizes, int n_in,
                              void* d_out, int out_size, void* d_ws, size_t ws_size,
                              hipStream_t stream) {
  const float* x = (const float*)d_in[0];   // [2048][1024]
  const float* w = (const float*)d_in[1];   // [1024][1024] (out_f, in_f)
  const float* b = (const float*)d_in[2];   // [1024]
  float* outp = (float*)d_out;              // [2048][1024] fp32

  char* ws_ = (char*)d_ws;
  u32* xB = (u32*)ws_;                        // [K/4][M] u32 bytes, 2 MiB
  u32* wB = (u32*)(ws_ + (size_t)(2 << 20));  // [K/4][N] u32 bytes, 1 MiB

  hipLaunchKernelGGL(prep_kernel, dim3(2048 + 1024), dim3(256), 0, stream,
                     x, w, xB, wB);
  hipLaunchKernelGGL(gemm_qfma, dim3(N_DIM / BN, M_DIM / BM), dim3(256), 0, stream,
                     xB, wB, b, outp);
}

// Round 12
// 119.715 us; speedup vs baseline: 1.7354x; 1.0175x over previous
//
#include <hip/hip_runtime.h>
#include <hip/hip_fp16.h>

// QLinear with per-k fp16 requantized accumulation (mptorch fma semantics).
// out = q16( q16_scan_fma( q8(x) @ q8(W)^T ) + q8(b) )
//
// Round-12 hybrid: x in f16 LDS (R3's proven layout: zero decode, 2-addr
// broadcast ds_read_b128), w in fp8 bytes LDS (R11's proven layout: one
// ds_read_b128 + 8 quarter-rate cvt per k-quad instead of two b128).
// Per wave-quad: LDS 3 instr (R3=4, R11=2), VALU 128 cyc (R3=64, R11=192)
// -> both pipes ~30 us/CU, max-pipe floor drops 41 -> ~31 us.
// pkfma chain and per-acc ascending-k order identical to R3/R11 (passed).

#define M_DIM 2048
#define N_DIM 1024
#define K_DIM 1024

#define BM 32
#define BN 128
#define BK 64
#define NCHUNK (K_DIM / BK)   // 16

typedef unsigned u32;
typedef float f32x2 __attribute__((ext_vector_type(2)));
typedef _Float16 f16x2 __attribute__((ext_vector_type(2)));

// exact E4M3 (exp=4, man=3) quantization of an fp32 value, result fp32
__device__ __forceinline__ float quant_e4m3(float v) {
  unsigned au = __float_as_uint(v) & 0x7fffffffu;
  if (au == 0u) return v;                 // +-0
  int e = (int)(au >> 23) - 127;          // floor(log2|v|) for normals
  if (e < -6) e = -6;                     // fp32 subnorms hit the clamp too
  float s  = __uint_as_float((unsigned)(130 - e) << 23);  // 2^(3-e), exact
  float is = __uint_as_float((unsigned)(124 + e) << 23);  // 2^(e-3), exact
  float r = rintf(v * s) * is;            // RNE (half-to-even), all steps exact
  return fminf(240.f, fmaxf(-240.f, r));
}

// exact encode of an E4M3-representable fp32 value to an OCP e4m3fn byte.
__device__ __forceinline__ u32 enc_e4m3(float v) {
  unsigned au = __float_as_uint(v);
  unsigned sg = (au >> 24) & 0x80u;
  unsigned a = au & 0x7fffffffu;
  if (a == 0u) return sg;                 // +-0
  int e = (int)(a >> 23) - 127;           // value is f32-normal (>= 2^-9)
  unsigned man = (a >> 20) & 7u;
  if (e >= -6) return sg | ((unsigned)(e + 7) << 3) | man;   // normal
  return sg | ((8u | man) >> (-6 - e));   // subnormal: multiples of 2^-9
}

// ---------- fused prep ----------
// blocks [0,2048): x [M][K] -> xP[K/2][M] u32 = {q(x[m][2t]), q(x[m][2t+1])}
//   as f16 pair (R3's proven x-branch, verbatim)
// blocks [2048,3072): w [N][K] -> wB u32[K/4][N] viewed as uint4[K/4][N/4];
//   entry (q, c) = { u32{n0k0,n1k0,n0k1,n1k1}, u32{n2k0,n3k0,n2k1,n3k1},
//                    u32{n0k2,n1k2,n0k3,n1k3}, u32{n2k2,n3k2,n2k3,n3k3} }
//   as e4m3 bytes (R10/R11's proven w-branch, verbatim)
__global__ __launch_bounds__(256) void prep_kernel(const float* __restrict__ x,
                                                   const float* __restrict__ w,
                                                   u32* __restrict__ xP,
                                                   u32* __restrict__ wB) {
  __shared__ float tile[32][33];
  const int tx = threadIdx.x & 31;
  const int ty = threadIdx.x >> 5;
  if (blockIdx.x < 2048) {
    const int c0 = (blockIdx.x & 31) * 32;   // k offset
    const int r0 = (blockIdx.x >> 5) * 32;   // m offset
#pragma unroll
    for (int i = 0; i < 4; i++) {
      int r = r0 + ty + i * 8;
      tile[ty + i * 8][tx] = quant_e4m3(x[(size_t)r * K_DIM + c0 + tx]);  // [m_l][k_l]
    }
    __syncthreads();
#pragma unroll
    for (int i = 0; i < 2; i++) {
      int tl = ty + i * 8;                   // k-pair local 0..15
      u32 lo = (u32)__half_as_ushort(__float2half(tile[tx][2 * tl]));
      u32 hi = (u32)__half_as_ushort(__float2half(tile[tx][2 * tl + 1]));
      xP[(size_t)(c0 / 2 + tl) * M_DIM + r0 + tx] = lo | (hi << 16);
    }
  } else {
    const int b = blockIdx.x - 2048;
    const int k0t = (b & 31) * 32;
    const int n0t = (b >> 5) * 32;
#pragma unroll
    for (int i = 0; i < 4; i++) {
      int n = n0t + ty + i * 8;
      tile[ty + i * 8][tx] = quant_e4m3(w[(size_t)n * K_DIM + k0t + tx]);  // [n_l][k_l]
    }
    __syncthreads();
    const int u = threadIdx.x & 3;          // u32 slot in uint4
    const int cl = (threadIdx.x >> 2) & 7;  // n-chunk local (4 n)
    const int ql = (threadIdx.x >> 5) & 7;  // k-quad local
    const int nl = 4 * cl + 2 * (u & 1);    // n base for this u32
    const int kl = 4 * ql + 2 * (u >> 1);   // k base for this u32
    u32 v = enc_e4m3(tile[nl][kl])
          | (enc_e4m3(tile[nl + 1][kl]) << 8)
          | (enc_e4m3(tile[nl][kl + 1]) << 16)
          | (enc_e4m3(tile[nl + 1][kl + 1]) << 24);
    wB[(size_t)(k0t / 4 + ql) * N_DIM + n0t + (cl << 2) + u] = v;
  }
}

// ---------- GEMM ----------

__device__ __forceinline__ void gld16(const void* g, void* l) {
  __builtin_amdgcn_global_load_lds((const __attribute__((address_space(1))) u32*)g,
                                   (__attribute__((address_space(3))) u32*)l, 16, 0, 0);
}

// decode one fp8 byte-pair (word HI of v) to packed fp16 pair {b0, b1}.
// exact: e4m3fn values are a subset of fp16; scale 1.0 is identity.
#if __has_builtin(__builtin_amdgcn_cvt_scalef32_pk_f16_fp8)
template <int HI>
__device__ __forceinline__ u32 fp8x2_h2(u32 v) {
  f16x2 h = __builtin_amdgcn_cvt_scalef32_pk_f16_fp8((int)v, 1.0f, HI != 0);
  return __builtin_bit_cast(u32, h);      // 1 instr per 2 values (quarter-rate)
}
#else
template <int HI>
__device__ __forceinline__ u32 fp8x2_h2(u32 v) {
  f32x2 f = __builtin_amdgcn_cvt_pk_f32_fp8((int)v, HI);
  u32 r;
  asm("v_cvt_pkrtz_f16_f32 %0, %1, %2" : "=v"(r) : "v"(f[0]), "v"(f[1]));
  return r;
}
#endif

// acc = pk_fma(splat(x.lo), w, acc)  -- first k of the packed x pair
__device__ __forceinline__ void pkfma_lo(u32& acc, u32 x, u32 w) {
  asm("v_pk_fma_f16 %0, %1, %2, %0 op_sel:[0,0,0] op_sel_hi:[0,1,1]"
      : "+v"(acc) : "v"(x), "v"(w));
}
// acc = pk_fma(splat(x.hi), w, acc)  -- second k of the packed x pair
__device__ __forceinline__ void pkfma_hi(u32& acc, u32 x, u32 w) {
  asm("v_pk_fma_f16 %0, %1, %2, %0 op_sel:[1,0,0] op_sel_hi:[1,1,1]"
      : "+v"(acc) : "v"(x), "v"(w));
}

// xP [K/2][M] u32 (f16 k-pair packed), wB u32[K/4][N] (e4m3 bytes), b [N],
// out [M][N] fp32.  256 threads; tile 32m x 128n; lane 4m x 4n;
// tn = tid&31, tm = tid>>5 (2 distinct x addrs per wave -> broadcast).
__global__ __launch_bounds__(256, 2) void gemm_qfma(const u32* __restrict__ xP,
                                                    const u32* __restrict__ wB,
                                                    const float* __restrict__ b,
                                                    float* __restrict__ outp) {
  __shared__ __align__(16) u32 xs[2][BK / 2][BM];    // 2 x 32 x 32 u32  =  8 KB
  __shared__ __align__(16) u32 wsu[2][BK / 4][BN];   // 2 x 16 x 128 u32 = 16 KB
  const int tid = threadIdx.x;
  const int tn = tid & 31;
  const int tm = tid >> 5;
  const int bn0 = blockIdx.x * BN;
  const int bm0 = blockIdx.y * BM;

  u32 acc[4][2];
#pragma unroll
  for (int i = 0; i < 4; i++) { acc[i][0] = 0u; acc[i][1] = 0u; }

  // staging: linear LDS (base + tid*16), per-lane global src.
  // x: 32 rows x 32 u32 = 4 KB -> 256 thr x 16 B (one gld16)   [R3 verbatim]
  // w: 16 rows x 128 u32 = 8 KB -> 2 x gld16                   [R11 verbatim]
  const u32* xsrc = xP + (size_t)(tid >> 3) * M_DIM + bm0 + ((tid & 7) << 2);
  const u32* wsrc = wB + (size_t)(tid >> 5) * N_DIM + bn0 + ((tid & 31) << 2);

  auto stage = [&](int ch, int buf) {
    gld16(xsrc + (size_t)ch * (BK / 2) * M_DIM, (char*)&xs[buf][0][0] + tid * 16);
    const u32* wp = wsrc + (size_t)ch * (BK / 4) * N_DIM;
    char* wl = (char*)&wsu[buf][0][0] + tid * 16;
    gld16(wp, wl);                                   // rows 0..7
    gld16(wp + (size_t)8 * N_DIM, wl + 4096);        // rows 8..15
  };

  auto compute = [&](int buf) {
#pragma unroll
    for (int q = 0; q < BK / 4; q++) {      // k-quad: k = 4q .. 4q+3
      const uint4 xv  = *reinterpret_cast<const uint4*>(&xs[buf][2 * q][tm << 2]);     // {k0,k1}
      const uint4 xv2 = *reinterpret_cast<const uint4*>(&xs[buf][2 * q + 1][tm << 2]); // {k2,k3}
      const uint4 wq  = *reinterpret_cast<const uint4*>(&wsu[buf][q][tn << 2]);
      // decode w: 8 quarter-rate cvts for the whole quad
      const u32 wk0a = fp8x2_h2<0>(wq.x);   // k0: n01
      const u32 wk1a = fp8x2_h2<1>(wq.x);   // k1: n01
      const u32 wk0b = fp8x2_h2<0>(wq.y);   // k0: n23
      const u32 wk1b = fp8x2_h2<1>(wq.y);   // k1: n23
      const u32 wk2a = fp8x2_h2<0>(wq.z);   // k2: n01
      const u32 wk3a = fp8x2_h2<1>(wq.z);   // k3: n01
      const u32 wk2b = fp8x2_h2<0>(wq.w);   // k2: n23
      const u32 wk3b = fp8x2_h2<1>(wq.w);   // k3: n23
      // strict k order per accumulator: k0 (lo), k1 (hi), k2 (lo), k3 (hi)
      pkfma_lo(acc[0][0], xv.x, wk0a); pkfma_lo(acc[0][1], xv.x, wk0b);
      pkfma_lo(acc[1][0], xv.y, wk0a); pkfma_lo(acc[1][1], xv.y, wk0b);
      pkfma_lo(acc[2][0], xv.z, wk0a); pkfma_lo(acc[2][1], xv.z, wk0b);
      pkfma_lo(acc[3][0], xv.w, wk0a); pkfma_lo(acc[3][1], xv.w, wk0b);
      pkfma_hi(acc[0][0], xv.x, wk1a); pkfma_hi(acc[0][1], xv.x, wk1b);
      pkfma_hi(acc[1][0], xv.y, wk1a); pkfma_hi(acc[1][1], xv.y, wk1b);
      pkfma_hi(acc[2][0], xv.z, wk1a); pkfma_hi(acc[2][1], xv.z, wk1b);
      pkfma_hi(acc[3][0], xv.w, wk1a); pkfma_hi(acc[3][1], xv.w, wk1b);
      pkfma_lo(acc[0][0], xv2.x, wk2a); pkfma_lo(acc[0][1], xv2.x, wk2b);
      pkfma_lo(acc[1][0], xv2.y, wk2a); pkfma_lo(acc[1][1], xv2.y, wk2b);
      pkfma_lo(acc[2][0], xv2.z, wk2a); pkfma_lo(acc[2][1], xv2.z, wk2b);
      pkfma_lo(acc[3][0], xv2.w, wk2a); pkfma_lo(acc[3][1], xv2.w, wk2b);
      pkfma_hi(acc[0][0], xv2.x, wk3a); pkfma_hi(acc[0][1], xv2.x, wk3b);
      pkfma_hi(acc[1][0], xv2.y, wk3a); pkfma_hi(acc[1][1], xv2.y, wk3b);
      pkfma_hi(acc[2][0], xv2.z, wk3a); pkfma_hi(acc[2][1], xv2.z, wk3b);
      pkfma_hi(acc[3][0], xv2.w, wk3a); pkfma_hi(acc[3][1], xv2.w, wk3b);
    }
  };

  stage(0, 0);
  __syncthreads();
#pragma unroll 1
  for (int ch = 0; ch < NCHUNK; ch += 2) {
    stage(ch + 1, 1);          // issue next chunk's loads before compute
    compute(0);
    __syncthreads();
    if (ch + 2 < NCHUNK) stage(ch + 2, 0);
    compute(1);
    __syncthreads();
  }

  // epilogue: out = fp16RNE(acc + q8(b)), stored fp32 (fp32 add exact here)
  const int nc = bn0 + (tn << 2);
  float4 bq;
  bq.x = quant_e4m3(b[nc + 0]);
  bq.y = quant_e4m3(b[nc + 1]);
  bq.z = quant_e4m3(b[nc + 2]);
  bq.w = quant_e4m3(b[nc + 3]);
#pragma unroll
  for (int i = 0; i < 4; i++) {
    __half2 a0 = *reinterpret_cast<__half2*>(&acc[i][0]);  // n0,n1
    __half2 a1 = *reinterpret_cast<__half2*>(&acc[i][1]);  // n2,n3
    float4 o;
    o.x = __half2float(__float2half(__low2float(a0)  + bq.x));
    o.y = __half2float(__float2half(__high2float(a0) + bq.y));
    o.z = __half2float(__float2half(__low2float(a1)  + bq.z));
    o.w = __half2float(__float2half(__high2float(a1) + bq.w));
    *reinterpret_cast<float4*>(
        outp + (size_t)(bm0 + (tm << 2) + i) * N_DIM + nc) = o;
  }
}

extern "C" void kernel_launch(void* const* d_in, const int* in_sizes, int n_in,
                              void* d_out, int out_size, void* d_ws, size_t ws_size,
                              hipStream_t stream) {
  const float* x = (const float*)d_in[0];   // [2048][1024]
  const float* w = (const float*)d_in[1];   // [1024][1024] (out_f, in_f)
  const float* b = (const float*)d_in[2];   // [1024]
  float* outp = (float*)d_out;              // [2048][1024] fp32

  char* ws_ = (char*)d_ws;
  u32* xP = (u32*)ws_;                        // [K/2][M] u32 f16-pairs, 4 MiB
  u32* wB = (u32*)(ws_ + (size_t)(4 << 20));  // [K/4][N] u32 bytes,     1 MiB

  hipLaunchKernelGGL(prep_kernel, dim3(2048 + 1024), dim3(256), 0, stream,
                     x, w, xP, wB);
  hipLaunchKernelGGL(gemm_qfma, dim3(N_DIM / BN, M_DIM / BM), dim3(256), 0, stream,
                     xP, wB, b, outp);
}

// Round 13
// 116.868 us; speedup vs baseline: 1.7777x; 1.0244x over previous
//
#include <hip/hip_runtime.h>
#include <hip/hip_fp16.h>

// QLinear with per-k fp16 requantized accumulation (mptorch fma semantics).
// out = q16( q16_scan_fma( q8(x) @ q8(W)^T ) + q8(b) )
//
// Round-13 = round-12 hybrid (x f16 LDS / w fp8 LDS, 3 ds_read_b128 +
// 8 quarter-rate cvt + 32 pk_fma per k-quad) + EXPLICIT 1-quad-ahead
// software pipeline of the LDS reads (named A/B register sets, unroll-by-2,
// all static indices). Diagnosis: R3/R11/R12 all show time ~= LDS + VALU
// with <10-25% overlap (convoy: 2 waves/SIMD in barrier lockstep, VGPR=40
// -> zero read-ahead). Prefetching q+1's reads under q's 128-cyc compute
// breaks the convoy; floor becomes max(VALU 33us, LDS 31us) ~= 33us.

#define M_DIM 2048
#define N_DIM 1024
#define K_DIM 1024

#define BM 32
#define BN 128
#define BK 64
#define NCHUNK (K_DIM / BK)   // 16

typedef unsigned u32;
typedef float f32x2 __attribute__((ext_vector_type(2)));
typedef _Float16 f16x2 __attribute__((ext_vector_type(2)));

// exact E4M3 (exp=4, man=3) quantization of an fp32 value, result fp32
__device__ __forceinline__ float quant_e4m3(float v) {
  unsigned au = __float_as_uint(v) & 0x7fffffffu;
  if (au == 0u) return v;                 // +-0
  int e = (int)(au >> 23) - 127;          // floor(log2|v|) for normals
  if (e < -6) e = -6;                     // fp32 subnorms hit the clamp too
  float s  = __uint_as_float((unsigned)(130 - e) << 23);  // 2^(3-e), exact
  float is = __uint_as_float((unsigned)(124 + e) << 23);  // 2^(e-3), exact
  float r = rintf(v * s) * is;            // RNE (half-to-even), all steps exact
  return fminf(240.f, fmaxf(-240.f, r));
}

// exact encode of an E4M3-representable fp32 value to an OCP e4m3fn byte.
__device__ __forceinline__ u32 enc_e4m3(float v) {
  unsigned au = __float_as_uint(v);
  unsigned sg = (au >> 24) & 0x80u;
  unsigned a = au & 0x7fffffffu;
  if (a == 0u) return sg;                 // +-0
  int e = (int)(a >> 23) - 127;           // value is f32-normal (>= 2^-9)
  unsigned man = (a >> 20) & 7u;
  if (e >= -6) return sg | ((unsigned)(e + 7) << 3) | man;   // normal
  return sg | ((8u | man) >> (-6 - e));   // subnormal: multiples of 2^-9
}

// ---------- fused prep (identical to round-12, proven) ----------
__global__ __launch_bounds__(256) void prep_kernel(const float* __restrict__ x,
                                                   const float* __restrict__ w,
                                                   u32* __restrict__ xP,
                                                   u32* __restrict__ wB) {
  __shared__ float tile[32][33];
  const int tx = threadIdx.x & 31;
  const int ty = threadIdx.x >> 5;
  if (blockIdx.x < 2048) {
    const int c0 = (blockIdx.x & 31) * 32;   // k offset
    const int r0 = (blockIdx.x >> 5) * 32;   // m offset
#pragma unroll
    for (int i = 0; i < 4; i++) {
      int r = r0 + ty + i * 8;
      tile[ty + i * 8][tx] = quant_e4m3(x[(size_t)r * K_DIM + c0 + tx]);  // [m_l][k_l]
    }
    __syncthreads();
#pragma unroll
    for (int i = 0; i < 2; i++) {
      int tl = ty + i * 8;                   // k-pair local 0..15
      u32 lo = (u32)__half_as_ushort(__float2half(tile[tx][2 * tl]));
      u32 hi = (u32)__half_as_ushort(__float2half(tile[tx][2 * tl + 1]));
      xP[(size_t)(c0 / 2 + tl) * M_DIM + r0 + tx] = lo | (hi << 16);
    }
  } else {
    const int b = blockIdx.x - 2048;
    const int k0t = (b & 31) * 32;
    const int n0t = (b >> 5) * 32;
#pragma unroll
    for (int i = 0; i < 4; i++) {
      int n = n0t + ty + i * 8;
      tile[ty + i * 8][tx] = quant_e4m3(w[(size_t)n * K_DIM + k0t + tx]);  // [n_l][k_l]
    }
    __syncthreads();
    const int u = threadIdx.x & 3;          // u32 slot in uint4
    const int cl = (threadIdx.x >> 2) & 7;  // n-chunk local (4 n)
    const int ql = (threadIdx.x >> 5) & 7;  // k-quad local
    const int nl = 4 * cl + 2 * (u & 1);    // n base for this u32
    const int kl = 4 * ql + 2 * (u >> 1);   // k base for this u32
    u32 v = enc_e4m3(tile[nl][kl])
          | (enc_e4m3(tile[nl + 1][kl]) << 8)
          | (enc_e4m3(tile[nl][kl + 1]) << 16)
          | (enc_e4m3(tile[nl + 1][kl + 1]) << 24);
    wB[(size_t)(k0t / 4 + ql) * N_DIM + n0t + (cl << 2) + u] = v;
  }
}

// ---------- GEMM ----------

__device__ __forceinline__ void gld16(const void* g, void* l) {
  __builtin_amdgcn_global_load_lds((const __attribute__((address_space(1))) u32*)g,
                                   (__attribute__((address_space(3))) u32*)l, 16, 0, 0);
}

// decode one fp8 byte-pair (word HI of v) to packed fp16 pair {b0, b1}.
#if __has_builtin(__builtin_amdgcn_cvt_scalef32_pk_f16_fp8)
template <int HI>
__device__ __forceinline__ u32 fp8x2_h2(u32 v) {
  f16x2 h = __builtin_amdgcn_cvt_scalef32_pk_f16_fp8((int)v, 1.0f, HI != 0);
  return __builtin_bit_cast(u32, h);      // 1 instr per 2 values (quarter-rate)
}
#else
template <int HI>
__device__ __forceinline__ u32 fp8x2_h2(u32 v) {
  f32x2 f = __builtin_amdgcn_cvt_pk_f32_fp8((int)v, HI);
  u32 r;
  asm("v_cvt_pkrtz_f16_f32 %0, %1, %2" : "=v"(r) : "v"(f[0]), "v"(f[1]));
  return r;
}
#endif

// acc = pk_fma(splat(x.lo), w, acc)  -- first k of the packed x pair
__device__ __forceinline__ void pkfma_lo(u32& acc, u32 x, u32 w) {
  asm("v_pk_fma_f16 %0, %1, %2, %0 op_sel:[0,0,0] op_sel_hi:[0,1,1]"
      : "+v"(acc) : "v"(x), "v"(w));
}
// acc = pk_fma(splat(x.hi), w, acc)  -- second k of the packed x pair
__device__ __forceinline__ void pkfma_hi(u32& acc, u32 x, u32 w) {
  asm("v_pk_fma_f16 %0, %1, %2, %0 op_sel:[1,0,0] op_sel_hi:[1,1,1]"
      : "+v"(acc) : "v"(x), "v"(w));
}

// xP [K/2][M] u32 (f16 k-pair packed), wB u32[K/4][N] (e4m3 bytes), b [N],
// out [M][N] fp32.  256 threads; tile 32m x 128n; lane 4m x 4n.
__global__ __launch_bounds__(256, 2) void gemm_qfma(const u32* __restrict__ xP,
                                                    const u32* __restrict__ wB,
                                                    const float* __restrict__ b,
                                                    float* __restrict__ outp) {
  __shared__ __align__(16) u32 xs[2][BK / 2][BM];    // 2 x 32 x 32 u32  =  8 KB
  __shared__ __align__(16) u32 wsu[2][BK / 4][BN];   // 2 x 16 x 128 u32 = 16 KB
  const int tid = threadIdx.x;
  const int tn = tid & 31;
  const int tm = tid >> 5;
  const int bn0 = blockIdx.x * BN;
  const int bm0 = blockIdx.y * BM;

  u32 acc[4][2];
#pragma unroll
  for (int i = 0; i < 4; i++) { acc[i][0] = 0u; acc[i][1] = 0u; }

  // staging: linear LDS (base + tid*16), per-lane global src.  [R12 verbatim]
  const u32* xsrc = xP + (size_t)(tid >> 3) * M_DIM + bm0 + ((tid & 7) << 2);
  const u32* wsrc = wB + (size_t)(tid >> 5) * N_DIM + bn0 + ((tid & 31) << 2);

  auto stage = [&](int ch, int buf) {
    gld16(xsrc + (size_t)ch * (BK / 2) * M_DIM, (char*)&xs[buf][0][0] + tid * 16);
    const u32* wp = wsrc + (size_t)ch * (BK / 4) * N_DIM;
    char* wl = (char*)&wsu[buf][0][0] + tid * 16;
    gld16(wp, wl);                                   // rows 0..7
    gld16(wp + (size_t)8 * N_DIM, wl + 4096);        // rows 8..15
  };

  // one k-quad: decode w (8 quarter-rate cvt) + 32 pk_fma.
  // strict k order per accumulator: k0 (lo), k1 (hi), k2 (lo), k3 (hi).
  auto quad = [&](const uint4& xv, const uint4& xv2, const uint4& wq) {
    const u32 wk0a = fp8x2_h2<0>(wq.x);   // k0: n01
    const u32 wk1a = fp8x2_h2<1>(wq.x);   // k1: n01
    const u32 wk0b = fp8x2_h2<0>(wq.y);   // k0: n23
    const u32 wk1b = fp8x2_h2<1>(wq.y);   // k1: n23
    const u32 wk2a = fp8x2_h2<0>(wq.z);   // k2: n01
    const u32 wk3a = fp8x2_h2<1>(wq.z);   // k3: n01
    const u32 wk2b = fp8x2_h2<0>(wq.w);   // k2: n23
    const u32 wk3b = fp8x2_h2<1>(wq.w);   // k3: n23
    pkfma_lo(acc[0][0], xv.x, wk0a); pkfma_lo(acc[0][1], xv.x, wk0b);
    pkfma_lo(acc[1][0], xv.y, wk0a); pkfma_lo(acc[1][1], xv.y, wk0b);
    pkfma_lo(acc[2][0], xv.z, wk0a); pkfma_lo(acc[2][1], xv.z, wk0b);
    pkfma_lo(acc[3][0], xv.w, wk0a); pkfma_lo(acc[3][1], xv.w, wk0b);
    pkfma_hi(acc[0][0], xv.x, wk1a); pkfma_hi(acc[0][1], xv.x, wk1b);
    pkfma_hi(acc[1][0], xv.y, wk1a); pkfma_hi(acc[1][1], xv.y, wk1b);
    pkfma_hi(acc[2][0], xv.z, wk1a); pkfma_hi(acc[2][1], xv.z, wk1b);
    pkfma_hi(acc[3][0], xv.w, wk1a); pkfma_hi(acc[3][1], xv.w, wk1b);
    pkfma_lo(acc[0][0], xv2.x, wk2a); pkfma_lo(acc[0][1], xv2.x, wk2b);
    pkfma_lo(acc[1][0], xv2.y, wk2a); pkfma_lo(acc[1][1], xv2.y, wk2b);
    pkfma_lo(acc[2][0], xv2.z, wk2a); pkfma_lo(acc[2][1], xv2.z, wk2b);
    pkfma_lo(acc[3][0], xv2.w, wk2a); pkfma_lo(acc[3][1], xv2.w, wk2b);
    pkfma_hi(acc[0][0], xv2.x, wk3a); pkfma_hi(acc[0][1], xv2.x, wk3b);
    pkfma_hi(acc[1][0], xv2.y, wk3a); pkfma_hi(acc[1][1], xv2.y, wk3b);
    pkfma_hi(acc[2][0], xv2.z, wk3a); pkfma_hi(acc[2][1], xv2.z, wk3b);
    pkfma_hi(acc[3][0], xv2.w, wk3a); pkfma_hi(acc[3][1], xv2.w, wk3b);
  };

  // compute with 1-quad-ahead LDS prefetch (A/B named sets, static indices)
  auto compute = [&](int buf) {
    const u32* xrow = &xs[buf][0][tm << 2];   // stride BM u32 per k-pair row
    const u32* wrow = &wsu[buf][0][tn << 2];  // stride BN u32 per k-quad row
#define XRD(kp)  (*reinterpret_cast<const uint4*>(xrow + (kp) * BM))
#define WRD(qq)  (*reinterpret_cast<const uint4*>(wrow + (qq) * BN))
    uint4 xvA = XRD(0), xv2A = XRD(1), wqA = WRD(0);          // quad 0
#pragma unroll
    for (int q = 0; q < BK / 4; q += 2) {
      // prefetch quad q+1 (always exists: BK/4 = 16 even)
      uint4 xvB = XRD(2 * q + 2), xv2B = XRD(2 * q + 3), wqB = WRD(q + 1);
      quad(xvA, xv2A, wqA);
      if (q + 2 < BK / 4) {   // prefetch quad q+2 (compile-time guard)
        xvA = XRD(2 * q + 4); xv2A = XRD(2 * q + 5); wqA = WRD(q + 2);
      }
      quad(xvB, xv2B, wqB);
    }
#undef XRD
#undef WRD
  };

  stage(0, 0);
  __syncthreads();
#pragma unroll 1
  for (int ch = 0; ch < NCHUNK; ch += 2) {
    stage(ch + 1, 1);          // issue next chunk's loads before compute
    compute(0);
    __syncthreads();
    if (ch + 2 < NCHUNK) stage(ch + 2, 0);
    compute(1);
    __syncthreads();
  }

  // epilogue: out = fp16RNE(acc + q8(b)), stored fp32 (fp32 add exact here)
  const int nc = bn0 + (tn << 2);
  float4 bq;
  bq.x = quant_e4m3(b[nc + 0]);
  bq.y = quant_e4m3(b[nc + 1]);
  bq.z = quant_e4m3(b[nc + 2]);
  bq.w = quant_e4m3(b[nc + 3]);
#pragma unroll
  for (int i = 0; i < 4; i++) {
    __half2 a0 = *reinterpret_cast<__half2*>(&acc[i][0]);  // n0,n1
    __half2 a1 = *reinterpret_cast<__half2*>(&acc[i][1]);  // n2,n3
    float4 o;
    o.x = __half2float(__float2half(__low2float(a0)  + bq.x));
    o.y = __half2float(__float2half(__high2float(a0) + bq.y));
    o.z = __half2float(__float2half(__low2float(a1)  + bq.z));
    o.w = __half2float(__float2half(__high2float(a1) + bq.w));
    *reinterpret_cast<float4*>(
        outp + (size_t)(bm0 + (tm << 2) + i) * N_DIM + nc) = o;
  }
}

extern "C" void kernel_launch(void* const* d_in, const int* in_sizes, int n_in,
                              void* d_out, int out_size, void* d_ws, size_t ws_size,
                              hipStream_t stream) {
  const float* x = (const float*)d_in[0];   // [2048][1024]
  const float* w = (const float*)d_in[1];   // [1024][1024] (out_f, in_f)
  const float* b = (const float*)d_in[2];   // [1024]
  float* outp = (float*)d_out;              // [2048][1024] fp32

  char* ws_ = (char*)d_ws;
  u32* xP = (u32*)ws_;                        // [K/2][M] u32 f16-pairs, 4 MiB
  u32* wB = (u32*)(ws_ + (size_t)(4 << 20));  // [K/4][N] u32 bytes,     1 MiB

  hipLaunchKernelGGL(prep_kernel, dim3(2048 + 1024), dim3(256), 0, stream,
                     x, w, xP, wB);
  hipLaunchKernelGGL(gemm_qfma, dim3(N_DIM / BN, M_DIM / BM), dim3(256), 0, stream,
                     xP, wB, b, outp);
}

// Round 14
// 116.351 us; speedup vs baseline: 1.7856x; 1.0044x over previous
//
#include <hip/hip_runtime.h>
#include <hip/hip_fp16.h>

// QLinear with per-k fp16 requantized accumulation (mptorch fma semantics).
// out = q16( q16_scan_fma( q8(x) @ q8(W)^T ) + q8(b) )
//
// Round-14 = round-12/13 hybrid (x f16 LDS / w fp8 LDS; per k-quad:
// 3 ds_read_b128 + 8 quarter-rate cvt + 32 pk_fma) with the software
// pipeline ENFORCED by sched_barrier(0) fences (R13's named-register
// version was re-sunk by the scheduler: VGPR stayed 40, time flat).
// Distance-2 rotation: reads for quad q+2 are fenced BEFORE quad q's
// VALU, so the compiler's own waitcnt pass emits counted lgkmcnt(6)
// instead of a cold lgkmcnt(0) every quad -- breaking the measured
// convoy (both pipes ~55% busy, complementary). Floor: max(LDS 30.7us,
// VALU 33us) vs 56us measured serial. No volatile loads, no manual
// waitcnt -> zero correctness risk; numerics identical to R12/R13.

#define M_DIM 2048
#define N_DIM 1024
#define K_DIM 1024

#define BM 32
#define BN 128
#define BK 64
#define NCHUNK (K_DIM / BK)   // 16

typedef unsigned u32;
typedef float f32x2 __attribute__((ext_vector_type(2)));
typedef _Float16 f16x2 __attribute__((ext_vector_type(2)));

// exact E4M3 (exp=4, man=3) quantization of an fp32 value, result fp32
__device__ __forceinline__ float quant_e4m3(float v) {
  unsigned au = __float_as_uint(v) & 0x7fffffffu;
  if (au == 0u) return v;                 // +-0
  int e = (int)(au >> 23) - 127;          // floor(log2|v|) for normals
  if (e < -6) e = -6;                     // fp32 subnorms hit the clamp too
  float s  = __uint_as_float((unsigned)(130 - e) << 23);  // 2^(3-e), exact
  float is = __uint_as_float((unsigned)(124 + e) << 23);  // 2^(e-3), exact
  float r = rintf(v * s) * is;            // RNE (half-to-even), all steps exact
  return fminf(240.f, fmaxf(-240.f, r));
}

// exact encode of an E4M3-representable fp32 value to an OCP e4m3fn byte.
__device__ __forceinline__ u32 enc_e4m3(float v) {
  unsigned au = __float_as_uint(v);
  unsigned sg = (au >> 24) & 0x80u;
  unsigned a = au & 0x7fffffffu;
  if (a == 0u) return sg;                 // +-0
  int e = (int)(a >> 23) - 127;           // value is f32-normal (>= 2^-9)
  unsigned man = (a >> 20) & 7u;
  if (e >= -6) return sg | ((unsigned)(e + 7) << 3) | man;   // normal
  return sg | ((8u | man) >> (-6 - e));   // subnormal: multiples of 2^-9
}

// ---------- fused prep (identical to round-12/13, proven) ----------
__global__ __launch_bounds__(256) void prep_kernel(const float* __restrict__ x,
                                                   const float* __restrict__ w,
                                                   u32* __restrict__ xP,
                                                   u32* __restrict__ wB) {
  __shared__ float tile[32][33];
  const int tx = threadIdx.x & 31;
  const int ty = threadIdx.x >> 5;
  if (blockIdx.x < 2048) {
    const int c0 = (blockIdx.x & 31) * 32;   // k offset
    const int r0 = (blockIdx.x >> 5) * 32;   // m offset
#pragma unroll
    for (int i = 0; i < 4; i++) {
      int r = r0 + ty + i * 8;
      tile[ty + i * 8][tx] = quant_e4m3(x[(size_t)r * K_DIM + c0 + tx]);  // [m_l][k_l]
    }
    __syncthreads();
#pragma unroll
    for (int i = 0; i < 2; i++) {
      int tl = ty + i * 8;                   // k-pair local 0..15
      u32 lo = (u32)__half_as_ushort(__float2half(tile[tx][2 * tl]));
      u32 hi = (u32)__half_as_ushort(__float2half(tile[tx][2 * tl + 1]));
      xP[(size_t)(c0 / 2 + tl) * M_DIM + r0 + tx] = lo | (hi << 16);
    }
  } else {
    const int b = blockIdx.x - 2048;
    const int k0t = (b & 31) * 32;
    const int n0t = (b >> 5) * 32;
#pragma unroll
    for (int i = 0; i < 4; i++) {
      int n = n0t + ty + i * 8;
      tile[ty + i * 8][tx] = quant_e4m3(w[(size_t)n * K_DIM + k0t + tx]);  // [n_l][k_l]
    }
    __syncthreads();
    const int u = threadIdx.x & 3;          // u32 slot in uint4
    const int cl = (threadIdx.x >> 2) & 7;  // n-chunk local (4 n)
    const int ql = (threadIdx.x >> 5) & 7;  // k-quad local
    const int nl = 4 * cl + 2 * (u & 1);    // n base for this u32
    const int kl = 4 * ql + 2 * (u >> 1);   // k base for this u32
    u32 v = enc_e4m3(tile[nl][kl])
          | (enc_e4m3(tile[nl + 1][kl]) << 8)
          | (enc_e4m3(tile[nl][kl + 1]) << 16)
          | (enc_e4m3(tile[nl + 1][kl + 1]) << 24);
    wB[(size_t)(k0t / 4 + ql) * N_DIM + n0t + (cl << 2) + u] = v;
  }
}

// ---------- GEMM ----------

__device__ __forceinline__ void gld16(const void* g, void* l) {
  __builtin_amdgcn_global_load_lds((const __attribute__((address_space(1))) u32*)g,
                                   (__attribute__((address_space(3))) u32*)l, 16, 0, 0);
}

// decode one fp8 byte-pair (word HI of v) to packed fp16 pair {b0, b1}.
#if __has_builtin(__builtin_amdgcn_cvt_scalef32_pk_f16_fp8)
template <int HI>
__device__ __forceinline__ u32 fp8x2_h2(u32 v) {
  f16x2 h = __builtin_amdgcn_cvt_scalef32_pk_f16_fp8((int)v, 1.0f, HI != 0);
  return __builtin_bit_cast(u32, h);      // 1 instr per 2 values (quarter-rate)
}
#else
template <int HI>
__device__ __forceinline__ u32 fp8x2_h2(u32 v) {
  f32x2 f = __builtin_amdgcn_cvt_pk_f32_fp8((int)v, HI);
  u32 r;
  asm("v_cvt_pkrtz_f16_f32 %0, %1, %2" : "=v"(r) : "v"(f[0]), "v"(f[1]));
  return r;
}
#endif

// acc = pk_fma(splat(x.lo), w, acc)  -- first k of the packed x pair
__device__ __forceinline__ void pkfma_lo(u32& acc, u32 x, u32 w) {
  asm("v_pk_fma_f16 %0, %1, %2, %0 op_sel:[0,0,0] op_sel_hi:[0,1,1]"
      : "+v"(acc) : "v"(x), "v"(w));
}
// acc = pk_fma(splat(x.hi), w, acc)  -- second k of the packed x pair
__device__ __forceinline__ void pkfma_hi(u32& acc, u32 x, u32 w) {
  asm("v_pk_fma_f16 %0, %1, %2, %0 op_sel:[1,0,0] op_sel_hi:[1,1,1]"
      : "+v"(acc) : "v"(x), "v"(w));
}

// xP [K/2][M] u32 (f16 k-pair packed), wB u32[K/4][N] (e4m3 bytes), b [N],
// out [M][N] fp32.  256 threads; tile 32m x 128n; lane 4m x 4n.
__global__ __launch_bounds__(256, 2) void gemm_qfma(const u32* __restrict__ xP,
                                                    const u32* __restrict__ wB,
                                                    const float* __restrict__ b,
                                                    float* __restrict__ outp) {
  __shared__ __align__(16) u32 xs[2][BK / 2][BM];    // 2 x 32 x 32 u32  =  8 KB
  __shared__ __align__(16) u32 wsu[2][BK / 4][BN];   // 2 x 16 x 128 u32 = 16 KB
  const int tid = threadIdx.x;
  const int tn = tid & 31;
  const int tm = tid >> 5;
  const int bn0 = blockIdx.x * BN;
  const int bm0 = blockIdx.y * BM;

  u32 acc[4][2];
#pragma unroll
  for (int i = 0; i < 4; i++) { acc[i][0] = 0u; acc[i][1] = 0u; }

  // staging: linear LDS (base + tid*16), per-lane global src.  [R12 verbatim]
  const u32* xsrc = xP + (size_t)(tid >> 3) * M_DIM + bm0 + ((tid & 7) << 2);
  const u32* wsrc = wB + (size_t)(tid >> 5) * N_DIM + bn0 + ((tid & 31) << 2);

  auto stage = [&](int ch, int buf) {
    gld16(xsrc + (size_t)ch * (BK / 2) * M_DIM, (char*)&xs[buf][0][0] + tid * 16);
    const u32* wp = wsrc + (size_t)ch * (BK / 4) * N_DIM;
    char* wl = (char*)&wsu[buf][0][0] + tid * 16;
    gld16(wp, wl);                                   // rows 0..7
    gld16(wp + (size_t)8 * N_DIM, wl + 4096);        // rows 8..15
  };

  // one k-quad: decode w (8 quarter-rate cvt) + 32 pk_fma.
  // strict k order per accumulator: k0 (lo), k1 (hi), k2 (lo), k3 (hi).
  auto quad = [&](const uint4& xv, const uint4& xv2, const uint4& wq) {
    const u32 wk0a = fp8x2_h2<0>(wq.x);   // k0: n01
    const u32 wk1a = fp8x2_h2<1>(wq.x);   // k1: n01
    const u32 wk0b = fp8x2_h2<0>(wq.y);   // k0: n23
    const u32 wk1b = fp8x2_h2<1>(wq.y);   // k1: n23
    const u32 wk2a = fp8x2_h2<0>(wq.z);   // k2: n01
    const u32 wk3a = fp8x2_h2<1>(wq.z);   // k3: n01
    const u32 wk2b = fp8x2_h2<0>(wq.w);   // k2: n23
    const u32 wk3b = fp8x2_h2<1>(wq.w);   // k3: n23
    pkfma_lo(acc[0][0], xv.x, wk0a); pkfma_lo(acc[0][1], xv.x, wk0b);
    pkfma_lo(acc[1][0], xv.y, wk0a); pkfma_lo(acc[1][1], xv.y, wk0b);
    pkfma_lo(acc[2][0], xv.z, wk0a); pkfma_lo(acc[2][1], xv.z, wk0b);
    pkfma_lo(acc[3][0], xv.w, wk0a); pkfma_lo(acc[3][1], xv.w, wk0b);
    pkfma_hi(acc[0][0], xv.x, wk1a); pkfma_hi(acc[0][1], xv.x, wk1b);
    pkfma_hi(acc[1][0], xv.y, wk1a); pkfma_hi(acc[1][1], xv.y, wk1b);
    pkfma_hi(acc[2][0], xv.z, wk1a); pkfma_hi(acc[2][1], xv.z, wk1b);
    pkfma_hi(acc[3][0], xv.w, wk1a); pkfma_hi(acc[3][1], xv.w, wk1b);
    pkfma_lo(acc[0][0], xv2.x, wk2a); pkfma_lo(acc[0][1], xv2.x, wk2b);
    pkfma_lo(acc[1][0], xv2.y, wk2a); pkfma_lo(acc[1][1], xv2.y, wk2b);
    pkfma_lo(acc[2][0], xv2.z, wk2a); pkfma_lo(acc[2][1], xv2.z, wk2b);
    pkfma_lo(acc[3][0], xv2.w, wk2a); pkfma_lo(acc[3][1], xv2.w, wk2b);
    pkfma_hi(acc[0][0], xv2.x, wk3a); pkfma_hi(acc[0][1], xv2.x, wk3b);
    pkfma_hi(acc[1][0], xv2.y, wk3a); pkfma_hi(acc[1][1], xv2.y, wk3b);
    pkfma_hi(acc[2][0], xv2.z, wk3a); pkfma_hi(acc[2][1], xv2.z, wk3b);
    pkfma_hi(acc[3][0], xv2.w, wk3a); pkfma_hi(acc[3][1], xv2.w, wk3b);
  };

  // compute with sched_barrier-ENFORCED distance-2 LDS pipeline.
  // Emitted order per quad q: [reads q+2] || fence || [decode+fma q] || fence
  // -> compiler's waitcnt pass emits counted lgkmcnt(6), never 0.
  auto compute = [&](int buf) {
    const u32* xrow = &xs[buf][0][tm << 2];   // stride BM u32 per k-pair row
    const u32* wrow = &wsu[buf][0][tn << 2];  // stride BN u32 per k-quad row
#define XRD(kp)  (*reinterpret_cast<const uint4*>(xrow + (kp) * BM))
#define WRD(qq)  (*reinterpret_cast<const uint4*>(wrow + (qq) * BN))
    uint4 xv[3], xv2[3], wq[3];               // rotation; %3 static after unroll
    xv[0] = XRD(0); xv2[0] = XRD(1); wq[0] = WRD(0);
    xv[1] = XRD(2); xv2[1] = XRD(3); wq[1] = WRD(1);
    __builtin_amdgcn_sched_barrier(0);
#pragma unroll
    for (int q = 0; q < BK / 4; q++) {        // BK/4 = 16, fully unrolled
      if (q + 2 < BK / 4) {
        const int s = (q + 2) % 3;            // compile-time after unroll
        xv[s] = XRD(2 * (q + 2)); xv2[s] = XRD(2 * (q + 2) + 1); wq[s] = WRD(q + 2);
      }
      __builtin_amdgcn_sched_barrier(0);
      quad(xv[q % 3], xv2[q % 3], wq[q % 3]);
      __builtin_amdgcn_sched_barrier(0);
    }
#undef XRD
#undef WRD
  };

  stage(0, 0);
  __syncthreads();
#pragma unroll 1
  for (int ch = 0; ch < NCHUNK; ch += 2) {
    stage(ch + 1, 1);          // issue next chunk's loads before compute
    compute(0);
    __syncthreads();
    if (ch + 2 < NCHUNK) stage(ch + 2, 0);
    compute(1);
    __syncthreads();
  }

  // epilogue: out = fp16RNE(acc + q8(b)), stored fp32 (fp32 add exact here)
  const int nc = bn0 + (tn << 2);
  float4 bq;
  bq.x = quant_e4m3(b[nc + 0]);
  bq.y = quant_e4m3(b[nc + 1]);
  bq.z = quant_e4m3(b[nc + 2]);
  bq.w = quant_e4m3(b[nc + 3]);
#pragma unroll
  for (int i = 0; i < 4; i++) {
    __half2 a0 = *reinterpret_cast<__half2*>(&acc[i][0]);  // n0,n1
    __half2 a1 = *reinterpret_cast<__half2*>(&acc[i][1]);  // n2,n3
    float4 o;
    o.x = __half2float(__float2half(__low2float(a0)  + bq.x));
    o.y = __half2float(__float2half(__high2float(a0) + bq.y));
    o.z = __half2float(__float2half(__low2float(a1)  + bq.z));
    o.w = __half2float(__float2half(__high2float(a1) + bq.w));
    *reinterpret_cast<float4*>(
        outp + (size_t)(bm0 + (tm << 2) + i) * N_DIM + nc) = o;
  }
}

extern "C" void kernel_launch(void* const* d_in, const int* in_sizes, int n_in,
                              void* d_out, int out_size, void* d_ws, size_t ws_size,
                              hipStream_t stream) {
  const float* x = (const float*)d_in[0];   // [2048][1024]
  const float* w = (const float*)d_in[1];   // [1024][1024] (out_f, in_f)
  const float* b = (const float*)d_in[2];   // [1024]
  float* outp = (float*)d_out;              // [2048][1024] fp32

  char* ws_ = (char*)d_ws;
  u32* xP = (u32*)ws_;                        // [K/2][M] u32 f16-pairs, 4 MiB
  u32* wB = (u32*)(ws_ + (size_t)(4 << 20));  // [K/4][N] u32 bytes,     1 MiB

  hipLaunchKernelGGL(prep_kernel, dim3(2048 + 1024), dim3(256), 0, stream,
                     x, w, xP, wB);
  hipLaunchKernelGGL(gemm_qfma, dim3(N_DIM / BN, M_DIM / BM), dim3(256), 0, stream,
                     xP, wB, b, outp);
}